// Round 8
// baseline (840.325 us; speedup 1.0000x reference)
//
#include <hip/hip_runtime.h>

#define N_NODES 50000
#define M_EDGES 800000
#define RP 50048  // padded row count for matrix buffers

typedef __bf16 bf16x8 __attribute__((ext_vector_type(8)));
typedef __bf16 bf16x4 __attribute__((ext_vector_type(4)));
typedef float  f32x4  __attribute__((ext_vector_type(4)));

static __device__ __forceinline__ unsigned enc_ord(float f) {
    unsigned b = __float_as_uint(f);
    return (b & 0x80000000u) ? ~b : (b | 0x80000000u);
}
static __device__ __forceinline__ float dec_ord(unsigned u) {
    unsigned b = (u & 0x80000000u) ? (u ^ 0x80000000u) : ~u;
    return __uint_as_float(b);
}
// bf16 pair packed in a uint: lo = bits[15:0], hi = bits[31:16]
static __device__ __forceinline__ float bflo(unsigned u) { return __uint_as_float(u << 16); }
static __device__ __forceinline__ float bfhi(unsigned u) { return __uint_as_float(u & 0xffff0000u); }
static __device__ __forceinline__ unsigned short bfbits(__bf16 b) {
    unsigned short u; __builtin_memcpy(&u, &b, 2); return u;
}

// async 16B global -> LDS DMA (LDS dest = wave-uniform base + lane*16)
static __device__ __forceinline__ void gload16(const void* g, void* l) {
    __builtin_amdgcn_global_load_lds(
        (const __attribute__((address_space(1))) void*)g,
        (__attribute__((address_space(3))) void*)l, 16, 0, 0);
}

// 8 async 16B DMAs; lds byte (buf*4+plane)*8192 + j*4096 + tid*16
// == plane base + slot*2048 + row*16 with slot = j*2+shi, row = tid&127.
#define STAGE(buf, kk) do {                                                   \
        int ke0 = (kk) + shi * 8;                                             \
        int ke1 = (kk) + (2 + shi) * 8;                                       \
        size_t lo0 = (size_t)(buf) * 32768 + (size_t)tid * 16;                \
        size_t lo1 = lo0 + 4096;                                              \
        gload16(gA0 + ke0, lds0 + lo0);                                       \
        gload16(gA0 + ke1, lds0 + lo1);                                       \
        gload16(gA1 + ke0, lds0 + 8192 + lo0);                                \
        gload16(gA1 + ke1, lds0 + 8192 + lo1);                                \
        gload16(gB0 + ke0, lds0 + 16384 + lo0);                               \
        gload16(gB0 + ke1, lds0 + 16384 + lo1);                               \
        gload16(gB1 + ke0, lds0 + 24576 + lo0);                               \
        gload16(gB1 + ke1, lds0 + 24576 + lo1);                               \
    } while (0)

// ---- ONE prep dispatch: weight splits (K|Q|V fused [768][256], Wagg/Wff),
// x split, bias concat, counts/cursor/gmax zero. [round-6 verbatim, passing]
__global__ __launch_bounds__(256) void prep_kernel(
    const float* __restrict__ Wk, const float* __restrict__ Wq,
    const float* __restrict__ Wv, const float* __restrict__ Wagg,
    const float* __restrict__ Wff,
    const float* __restrict__ bk, const float* __restrict__ bq,
    const float* __restrict__ bv,
    const float* __restrict__ X,
    __bf16* __restrict__ WHq, __bf16* __restrict__ WLq,
    __bf16* __restrict__ WaH, __bf16* __restrict__ WaL,
    __bf16* __restrict__ WfH, __bf16* __restrict__ WfL,
    float* __restrict__ bqkv, __bf16* __restrict__ xh, __bf16* __restrict__ xl,
    int* __restrict__ counts, int* __restrict__ cursor, unsigned* __restrict__ gmax) {
    int gid = blockIdx.x * 256 + threadIdx.x;
    int stride = gridDim.x * 256;
    for (int i = gid; i < 65536; i += stride) {
        int n = i >> 8, k = i & 255;
        size_t src = (size_t)k * 256 + n;
        float v; __bf16 h;
        v = Wk[src];   h = (__bf16)v; WHq[(size_t)n * 256 + k] = h;
                       WLq[(size_t)n * 256 + k] = (__bf16)(v - (float)h);
        v = Wq[src];   h = (__bf16)v; WHq[(size_t)(256 + n) * 256 + k] = h;
                       WLq[(size_t)(256 + n) * 256 + k] = (__bf16)(v - (float)h);
        v = Wv[src];   h = (__bf16)v; WHq[(size_t)(512 + n) * 256 + k] = h;
                       WLq[(size_t)(512 + n) * 256 + k] = (__bf16)(v - (float)h);
        v = Wagg[src]; h = (__bf16)v; WaH[i] = h; WaL[i] = (__bf16)(v - (float)h);
        v = Wff[src];  h = (__bf16)v; WfH[i] = h; WfL[i] = (__bf16)(v - (float)h);
    }
    const size_t nx = (size_t)N_NODES * 256 / 4;
    for (size_t i = gid; i < nx; i += stride) {
        float4 v = *(const float4*)(X + i * 4);
        bf16x4 hh, ll;
        hh[0] = (__bf16)v.x; ll[0] = (__bf16)(v.x - (float)hh[0]);
        hh[1] = (__bf16)v.y; ll[1] = (__bf16)(v.y - (float)hh[1]);
        hh[2] = (__bf16)v.z; ll[2] = (__bf16)(v.z - (float)hh[2]);
        hh[3] = (__bf16)v.w; ll[3] = (__bf16)(v.w - (float)hh[3]);
        *(bf16x4*)(xh + i * 4) = hh;
        *(bf16x4*)(xl + i * 4) = ll;
    }
    for (int i = gid; i < 768; i += stride)
        bqkv[i] = (i < 256) ? bk[i] : ((i < 512) ? bq[i - 256] : bv[i - 512]);
    for (int i = gid; i < N_NODES; i += stride) { counts[i] = 0; cursor[i] = 0; }
    if (gid == 0) *gmax = 0u;
}

// ---- FUSED K|Q|V projection GEMM, XCD-chunked bijective swizzle: the 6
// col-blocks sharing an A-slice run consecutively on ONE XCD (y-fastest
// within chunk) -> A fetched ~once per slice instead of 6x.
__global__ __launch_bounds__(256) void gemm_qkv(
    const __bf16* __restrict__ Ah, const __bf16* __restrict__ Al,
    const __bf16* __restrict__ Bth, const __bf16* __restrict__ Btl,
    const float* __restrict__ bqkv,
    __bf16* __restrict__ Kb, float* __restrict__ Qo, __bf16* __restrict__ Vb) {
    __shared__ __attribute__((aligned(16))) __bf16 sm[2][4][4][128][8];

    // bijective XCD chunking (m204 form), NB = 391*6 = 2346
    const int NB = 2346, q = NB / 8, r = NB % 8;   // 293, 2
    int bid = blockIdx.x;
    int xcd = bid & 7, i0 = bid >> 3;
    int logical = (xcd < r ? xcd * (q + 1) : r * (q + 1) + (xcd - r) * q) + i0;
    int by = logical % 6;
    int bx = logical / 6;
    int row0 = bx * 128;
    int n0   = by * 128;   // fused output col base, 0..640

    int tid  = threadIdx.x;
    int lane = tid & 63, wave = tid >> 6;
    int wm = (wave >> 1) * 64, wn = (wave & 1) * 64;

    f32x4 acc[4][4];
    #pragma unroll
    for (int i = 0; i < 4; i++)
        #pragma unroll
        for (int j = 0; j < 4; j++) acc[i][j] = (f32x4)(0.f);

    int srow = tid & 127;
    int shi  = tid >> 7;
    const __bf16* gA0 = Ah  + (size_t)(row0 + srow) * 256;
    const __bf16* gA1 = Al  + (size_t)(row0 + srow) * 256;
    const __bf16* gB0 = Bth + (size_t)(n0 + srow) * 256;
    const __bf16* gB1 = Btl + (size_t)(n0 + srow) * 256;
    char* lds0 = (char*)&sm[0][0][0][0][0];

    STAGE(0, 0);
    __syncthreads();

    int h = lane >> 4;
    int m_base = wm + (lane & 15);
    int n_base = wn + (lane & 15);

    for (int t = 0; t < 8; t++) {
        int cur = t & 1;
        if (t < 7) STAGE(cur ^ 1, (t + 1) * 32);
        bf16x8 ahf[4], alf[4], bhf[4], blf[4];
        #pragma unroll
        for (int mt = 0; mt < 4; mt++) {
            ahf[mt] = *(const bf16x8*)&sm[cur][0][h][m_base + mt * 16][0];
            alf[mt] = *(const bf16x8*)&sm[cur][1][h][m_base + mt * 16][0];
        }
        #pragma unroll
        for (int nt = 0; nt < 4; nt++) {
            bhf[nt] = *(const bf16x8*)&sm[cur][2][h][n_base + nt * 16][0];
            blf[nt] = *(const bf16x8*)&sm[cur][3][h][n_base + nt * 16][0];
        }
        #pragma unroll
        for (int mt = 0; mt < 4; mt++)
            #pragma unroll
            for (int nt = 0; nt < 4; nt++) {
                acc[mt][nt] = __builtin_amdgcn_mfma_f32_16x16x32_bf16(ahf[mt], bhf[nt], acc[mt][nt], 0, 0, 0);
                acc[mt][nt] = __builtin_amdgcn_mfma_f32_16x16x32_bf16(alf[mt], bhf[nt], acc[mt][nt], 0, 0, 0);
                acc[mt][nt] = __builtin_amdgcn_mfma_f32_16x16x32_bf16(ahf[mt], blf[nt], acc[mt][nt], 0, 0, 0);
            }
        __syncthreads();
    }

    #pragma unroll
    for (int mt = 0; mt < 4; mt++) {
        #pragma unroll
        for (int nt = 0; nt < 4; nt++) {
            int cg = n0 + wn + nt * 16 + (lane & 15);   // fused col 0..767
            #pragma unroll
            for (int rr = 0; rr < 4; rr++) {
                int row = row0 + wm + mt * 16 + (lane >> 4) * 4 + rr;
                if (row < N_NODES) {
                    float v = acc[mt][nt][rr] + bqkv[cg];
                    if (cg < 256)      Kb[(size_t)row * 256 + cg] = (__bf16)v;
                    else if (cg < 512) Qo[(size_t)row * 256 + (cg - 256)] = v;
                    else               Vb[(size_t)row * 256 + (cg - 512)] = (__bf16)v;
                }
            }
        }
    }
}

// ---- CSR build [round-6 verbatim, passing] ----
__global__ void hist_kernel(const int* __restrict__ recv, int* __restrict__ counts) {
    int t = blockIdx.x * 256 + threadIdx.x;
    if (t < M_EDGES) atomicAdd(&counts[recv[t]], 1);
}

__global__ void scan_kernel(const int* __restrict__ counts, int* __restrict__ offsets) {
    __shared__ int part[256];
    int t = threadIdx.x;
    const int per = (N_NODES + 255) / 256;
    int start = t * per;
    int end = min(start + per, N_NODES);
    int s = 0;
    for (int i = start; i < end; i++) s += counts[i];
    part[t] = s;
    __syncthreads();
    if (t == 0) {
        int acc = 0;
        for (int i = 0; i < 256; i++) { int v = part[i]; part[i] = acc; acc += v; }
    }
    __syncthreads();
    int acc = part[t];
    for (int i = start; i < end; i++) { offsets[i] = acc; acc += counts[i]; }
    if (end == N_NODES && start < N_NODES) offsets[N_NODES] = acc;
}

__global__ void fill_kernel(const int* __restrict__ recv, const int* __restrict__ send,
                            const int* __restrict__ offsets,
                            int* __restrict__ cursor, int* __restrict__ ssorted,
                            int* __restrict__ rsorted) {
    int t = blockIdx.x * 256 + threadIdx.x;
    if (t < M_EDGES) {
        int r = recv[t];
        int pos = offsets[r] + atomicAdd(&cursor[r], 1);
        ssorted[pos] = send[t];
        rsorted[pos] = r;
    }
}

// ---- edge logits [round-6 verbatim, passing: 120.4 us @ 1024 blocks]
__global__ __launch_bounds__(256) void qk_csr_kernel(
    const int* __restrict__ ssorted, const int* __restrict__ rsorted,
    const float* __restrict__ Q, const unsigned short* __restrict__ Kb,
    float* __restrict__ qks, unsigned* __restrict__ gmax) {
    int wave_id = (blockIdx.x * 256 + threadIdx.x) >> 6;
    int lane = threadIdx.x & 63;
    int e_slot = lane >> 5;        // which edge of the pair
    int sl = lane & 31;            // 16B chunk within row
    const int nwaves = (gridDim.x * 256) >> 6;
    const int npairs = M_EDGES / 2;
    float wmax = -INFINITY;
    for (int pp = wave_id; pp < npairs; pp += 4 * nwaves) {
        int ep[4]; bool valid[4];
        #pragma unroll
        for (int u = 0; u < 4; u++) {
            int p = pp + u * nwaves;
            valid[u] = p < npairs;
            ep[u] = (valid[u] ? p : pp) * 2 + e_slot;
        }
        int si[4], ri[4];
        #pragma unroll
        for (int u = 0; u < 4; u++) { si[u] = ssorted[ep[u]]; ri[u] = rsorted[ep[u]]; }
        uint4 kv[4]; float4 qa[4], qb[4];
        #pragma unroll
        for (int u = 0; u < 4; u++) {
            kv[u] = *(const uint4*)(Kb + (size_t)si[u] * 256 + sl * 8);
            qa[u] = *(const float4*)(Q + (size_t)ri[u] * 256 + sl * 8);
            qb[u] = *(const float4*)(Q + (size_t)ri[u] * 256 + sl * 8 + 4);
        }
        #pragma unroll
        for (int u = 0; u < 4; u++) {
            float d = qa[u].x * bflo(kv[u].x) + qa[u].y * bfhi(kv[u].x)
                    + qa[u].z * bflo(kv[u].y) + qa[u].w * bfhi(kv[u].y)
                    + qb[u].x * bflo(kv[u].z) + qb[u].y * bfhi(kv[u].z)
                    + qb[u].z * bflo(kv[u].w) + qb[u].w * bfhi(kv[u].w);
            d += __shfl_xor(d, 1);
            d += __shfl_xor(d, 2);
            wmax = fmaxf(wmax, d);
            if ((sl & 3) == 0 && valid[u])
                qks[(size_t)ep[u] * 8 + (sl >> 2)] = d;
        }
    }
    wmax = fmaxf(wmax, __shfl_xor(wmax, 1));
    wmax = fmaxf(wmax, __shfl_xor(wmax, 2));
    wmax = fmaxf(wmax, __shfl_xor(wmax, 4));
    wmax = fmaxf(wmax, __shfl_xor(wmax, 8));
    wmax = fmaxf(wmax, __shfl_xor(wmax, 16));
    wmax = fmaxf(wmax, __shfl_xor(wmax, 32));
    if (lane == 0 && wmax > -INFINITY) atomicMax(gmax, enc_ord(wmax));
}

// ---- node aggregation [round-6 verbatim, passing]
__global__ __launch_bounds__(256) void node_agg_kernel(
    const int* __restrict__ offsets, const int* __restrict__ ssorted,
    const float* __restrict__ qks, const unsigned short* __restrict__ Vb,
    const unsigned* __restrict__ gmax,
    __bf16* __restrict__ msgH, __bf16* __restrict__ msgL) {
    int wave_id = (blockIdx.x * 256 + threadIdx.x) >> 6;
    int lane = threadIdx.x & 63;   // columns lane*4 .. lane*4+3
    int h = lane >> 3;             // head of these columns
    const int nwaves = (gridDim.x * 256) >> 6;
    const int per = (N_NODES + nwaves - 1) / nwaves;
    int n0 = wave_id * per;
    int nend = min(n0 + per, N_NODES);
    float scale = 3.0f / dec_ord(*gmax);
    for (int n = n0; n < nend; n++) {
        int off = offsets[n];
        int deg = offsets[n + 1] - off;
        float sum = 0.f, a0 = 0.f, a1 = 0.f, a2 = 0.f, a3 = 0.f;
        for (int b = 0; b < deg; b += 64) {
            int bn = min(64, deg - b);
            int idxb = ssorted[off + b + min(lane, bn - 1)];
            #define VROW(i) (*(const uint2*)(Vb + \
                (size_t)__shfl(idxb, min((i), bn - 1)) * 256 + lane * 4))
            #define QKL(i) qks[(size_t)(off + b + min((i), bn - 1)) * 8 + h]
            uint2 v0 = VROW(0);
            uint2 v1 = VROW(1);
            float q0 = QKL(0);
            float q1 = QKL(1);
            for (int i = 0; i < bn; i++) {
                uint2 vc = v0; v0 = v1; v1 = VROW(i + 2);
                float qc = q0; q0 = q1; q1 = QKL(i + 2);
                float a = __expf(qc * scale);
                sum += a;
                a0 += a * bflo(vc.x); a1 += a * bfhi(vc.x);
                a2 += a * bflo(vc.y); a3 += a * bfhi(vc.y);
            }
            #undef VROW
            #undef QKL
        }
        float inv = (deg > 0) ? 1.0f / (sum * 5.65685424949238f) : 0.f;  // sqrt(32)
        float r0 = fmaxf(a0 * inv, 0.f), r1 = fmaxf(a1 * inv, 0.f);
        float r2 = fmaxf(a2 * inv, 0.f), r3 = fmaxf(a3 * inv, 0.f);
        bf16x4 hv, lv;
        hv[0] = (__bf16)r0; lv[0] = (__bf16)(r0 - (float)hv[0]);
        hv[1] = (__bf16)r1; lv[1] = (__bf16)(r1 - (float)hv[1]);
        hv[2] = (__bf16)r2; lv[2] = (__bf16)(r2 - (float)hv[2]);
        hv[3] = (__bf16)r3; lv[3] = (__bf16)(r3 - (float)hv[3]);
        *(bf16x4*)(msgH + (size_t)n * 256 + lane * 4) = hv;
        *(bf16x4*)(msgL + (size_t)n * 256 + lane * 4) = lv;
    }
}

// ---- FUSED MLP: out = x + relu(relu(msg@Wagg+bagg)@Wff+bff), one dispatch.
// Phase A: hid[128][256] in registers (two n-halves, identical staging/MFMA
// order to the old Wagg GEMM -> bit-identical hid). Phase B: per-k-slot LDS
// exchange of register-resident hid + Wff staging (k ascending, hh/lh/hl
// order -> bit-identical out). Hid never touches HBM. s-loop FULLY UNROLLED
// so all hidp indices are compile-time (rule #20: no scratch).
__global__ __launch_bounds__(256) void mlp_fused(
    const __bf16* __restrict__ msgH, const __bf16* __restrict__ msgL,
    const __bf16* __restrict__ WaH, const __bf16* __restrict__ WaL,
    const __bf16* __restrict__ WfH, const __bf16* __restrict__ WfL,
    const float* __restrict__ bagg, const float* __restrict__ bff,
    const float* __restrict__ x, float* __restrict__ out) {
    __shared__ __attribute__((aligned(16))) __bf16 sm[2][4][4][128][8];   // 64 KB

    int row0 = blockIdx.x * 128;
    int tid  = threadIdx.x;
    int lane = tid & 63, wave = tid >> 6;
    int wm = (wave >> 1) * 64, wn = (wave & 1) * 64;
    int srow = tid & 127;
    int shi  = tid >> 7;
    char* lds0 = (char*)&sm[0][0][0][0][0];
    int h = lane >> 4;
    int m_base = wm + (lane & 15);
    int n_base = wn + (lane & 15);

    // ---- phase A: hid = relu(msg @ Wagg + bagg), two col-halves
    f32x4 acc1[2][4][4];
    #pragma unroll
    for (int nh = 0; nh < 2; nh++)
        #pragma unroll
        for (int i = 0; i < 4; i++)
            #pragma unroll
            for (int j = 0; j < 4; j++) acc1[nh][i][j] = (f32x4)(0.f);

    const __bf16* gA0 = msgH + (size_t)(row0 + srow) * 256;
    const __bf16* gA1 = msgL + (size_t)(row0 + srow) * 256;
    const __bf16* gB0;
    const __bf16* gB1;

    #pragma unroll
    for (int nh = 0; nh < 2; nh++) {
        gB0 = WaH + (size_t)(nh * 128 + srow) * 256;
        gB1 = WaL + (size_t)(nh * 128 + srow) * 256;
        STAGE(0, 0);
        __syncthreads();
        for (int t = 0; t < 8; t++) {
            int cur = t & 1;
            if (t < 7) STAGE(cur ^ 1, (t + 1) * 32);
            bf16x8 ahf[4], alf[4], bhf[4], blf[4];
            #pragma unroll
            for (int mt = 0; mt < 4; mt++) {
                ahf[mt] = *(const bf16x8*)&sm[cur][0][h][m_base + mt * 16][0];
                alf[mt] = *(const bf16x8*)&sm[cur][1][h][m_base + mt * 16][0];
            }
            #pragma unroll
            for (int nt = 0; nt < 4; nt++) {
                bhf[nt] = *(const bf16x8*)&sm[cur][2][h][n_base + nt * 16][0];
                blf[nt] = *(const bf16x8*)&sm[cur][3][h][n_base + nt * 16][0];
            }
            #pragma unroll
            for (int mt = 0; mt < 4; mt++)
                #pragma unroll
                for (int nt = 0; nt < 4; nt++) {
                    acc1[nh][mt][nt] = __builtin_amdgcn_mfma_f32_16x16x32_bf16(ahf[mt], bhf[nt], acc1[nh][mt][nt], 0, 0, 0);
                    acc1[nh][mt][nt] = __builtin_amdgcn_mfma_f32_16x16x32_bf16(alf[mt], bhf[nt], acc1[nh][mt][nt], 0, 0, 0);
                    acc1[nh][mt][nt] = __builtin_amdgcn_mfma_f32_16x16x32_bf16(ahf[mt], blf[nt], acc1[nh][mt][nt], 0, 0, 0);
                }
            __syncthreads();
        }
    }

    // bias + relu + split-bf16, packed H | L<<16 per element
    unsigned hidp[2][4][4][4];
    #pragma unroll
    for (int nh = 0; nh < 2; nh++)
        #pragma unroll
        for (int mt = 0; mt < 4; mt++)
            #pragma unroll
            for (int nt = 0; nt < 4; nt++)
                #pragma unroll
                for (int rr = 0; rr < 4; rr++) {
                    int col = nh * 128 + wn + nt * 16 + (lane & 15);
                    float v = acc1[nh][mt][nt][rr] + bagg[col];
                    v = fmaxf(v, 0.f);
                    __bf16 hh = (__bf16)v;
                    __bf16 hl = (__bf16)(v - (float)hh);
                    hidp[nh][mt][nt][rr] =
                        (unsigned)bfbits(hh) | ((unsigned)bfbits(hl) << 16);
                }

    // ---- phase B: out = x + relu(hid @ Wff + bff), per k-slot LDS exchange
    unsigned short* chunkw = (unsigned short*)lds0;              // [2][4][128][8]
    const __bf16*   chunkb = (const __bf16*)lds0;
    unsigned short* b2w    = (unsigned short*)(lds0 + 16384);    // [2][4][128][8]
    const __bf16*   b2b    = (const __bf16*)(lds0 + 16384);

    for (int oh = 0; oh < 2; oh++) {
        f32x4 acc2[4][4];
        #pragma unroll
        for (int i = 0; i < 4; i++)
            #pragma unroll
            for (int j = 0; j < 4; j++) acc2[i][j] = (f32x4)(0.f);

        #pragma unroll
        for (int s = 0; s < 8; s++) {
            __syncthreads();   // previous iteration's LDS reads done
            // (a) owning waves write hid slot s (32 cols) into chunk
            int nh = s >> 2, sq = s & 3;   // compile-time (s unrolled)
            if (wn == ((sq >= 2) ? 64 : 0)) {
                int nt0 = (sq & 1) * 2;
                #pragma unroll
                for (int mt = 0; mt < 4; mt++)
                    #pragma unroll
                    for (int j = 0; j < 2; j++) {
                        int nt = nt0 + j;
                        int kc = (wn + nt * 16 + (lane & 15)) - 32 * sq;  // 0..31
                        int ks = kc >> 3, e = kc & 7;
                        #pragma unroll
                        for (int rr = 0; rr < 4; rr++) {
                            int row = wm + mt * 16 + (lane >> 4) * 4 + rr;
                            unsigned u = hidp[nh][mt][nt][rr];
                            chunkw[(size_t)ks * 1024 + row * 8 + e] =
                                (unsigned short)(u & 0xffffu);
                            chunkw[(size_t)(4 + ks) * 1024 + row * 8 + e] =
                                (unsigned short)(u >> 16);
                        }
                    }
            }
            // (b) stage Wff tile [128 outcols][32 k] split planes
            {
                int ks0 = shi * 2;
                #pragma unroll
                for (int j = 0; j < 2; j++) {
                    int ks = ks0 + j;
                    gload16(WfH + (size_t)(oh * 128 + srow) * 256 + 32 * s + ks * 8,
                            (char*)b2w + (size_t)ks * 2048 + srow * 16);
                    gload16(WfL + (size_t)(oh * 128 + srow) * 256 + 32 * s + ks * 8,
                            (char*)b2w + (size_t)(4 + ks) * 2048 + srow * 16);
                }
            }
            __syncthreads();   // ds-writes + DMA drained
            // (c) MFMA
            bf16x8 a2h[4], a2l[4], b2h[4], b2l[4];
            #pragma unroll
            for (int mt = 0; mt < 4; mt++) {
                a2h[mt] = *(const bf16x8*)&chunkb[(size_t)h * 1024 + (m_base + mt * 16) * 8];
                a2l[mt] = *(const bf16x8*)&chunkb[(size_t)(4 + h) * 1024 + (m_base + mt * 16) * 8];
            }
            #pragma unroll
            for (int nt = 0; nt < 4; nt++) {
                b2h[nt] = *(const bf16x8*)&b2b[(size_t)h * 1024 + (n_base + nt * 16) * 8];
                b2l[nt] = *(const bf16x8*)&b2b[(size_t)(4 + h) * 1024 + (n_base + nt * 16) * 8];
            }
            #pragma unroll
            for (int mt = 0; mt < 4; mt++)
                #pragma unroll
                for (int nt = 0; nt < 4; nt++) {
                    acc2[mt][nt] = __builtin_amdgcn_mfma_f32_16x16x32_bf16(a2h[mt], b2h[nt], acc2[mt][nt], 0, 0, 0);
                    acc2[mt][nt] = __builtin_amdgcn_mfma_f32_16x16x32_bf16(a2l[mt], b2h[nt], acc2[mt][nt], 0, 0, 0);
                    acc2[mt][nt] = __builtin_amdgcn_mfma_f32_16x16x32_bf16(a2h[mt], b2l[nt], acc2[mt][nt], 0, 0, 0);
                }
        }
        // epilogue for this out col-half
        #pragma unroll
        for (int mt = 0; mt < 4; mt++)
            #pragma unroll
            for (int nt = 0; nt < 4; nt++) {
                int oc = oh * 128 + wn + nt * 16 + (lane & 15);
                #pragma unroll
                for (int rr = 0; rr < 4; rr++) {
                    int row = row0 + wm + mt * 16 + (lane >> 4) * 4 + rr;
                    if (row < N_NODES) {
                        float v = acc2[mt][nt][rr] + bff[oc];
                        v = fmaxf(v, 0.f);
                        size_t idx = (size_t)row * 256 + oc;
                        out[idx] = v + x[idx];
                    }
                }
            }
    }
}

extern "C" void kernel_launch(void* const* d_in, const int* in_sizes, int n_in,
                              void* d_out, int out_size, void* d_ws, size_t ws_size,
                              hipStream_t stream) {
    const float* x    = (const float*)d_in[0];
    const int*   edge = (const int*)d_in[1];
    const int*   recv = edge;
    const int*   send = edge + M_EDGES;
    const float* Wk   = (const float*)d_in[2];
    const float* bk   = (const float*)d_in[3];
    const float* Wq   = (const float*)d_in[4];
    const float* bq   = (const float*)d_in[5];
    const float* Wv   = (const float*)d_in[6];
    const float* bv   = (const float*)d_in[7];
    const float* Wagg = (const float*)d_in[8];
    const float* bagg = (const float*)d_in[9];
    const float* Wff  = (const float*)d_in[10];
    const float* bff  = (const float*)d_in[11];
    float* out = (float*)d_out;

    float*  Qbuf  = (float*)d_ws;                       // RP*256 f32
    float*  reg2  = Qbuf + (size_t)RP * 256;            // RP*256 f32 multi-use
    float*  qks   = reg2 + (size_t)RP * 256;
    __bf16* Kbf   = (__bf16*)(qks + (size_t)M_EDGES * 8);
    __bf16* Vbf   = Kbf + (size_t)RP * 256;
    int* counts   = (int*)(Vbf + (size_t)RP * 256);
    int* cursor   = counts + N_NODES;
    int* offsets  = cursor + N_NODES;
    int* ssorted  = offsets + N_NODES + 1;
    unsigned* gmax = (unsigned*)(ssorted + M_EDGES);
    __bf16* wt    = (__bf16*)(gmax + 1);
    __bf16* WHq = wt;                    // [768][256]
    __bf16* WLq = wt + 3 * 65536;        // [768][256]
    __bf16* WaH = wt + 6 * 65536;  __bf16* WaL = wt + 7 * 65536;
    __bf16* WfH = wt + 8 * 65536;  __bf16* WfL = wt + 9 * 65536;
    float* bqkv = (float*)(wt + 10 * 65536);   // [768]
    // reg2 overlays (strictly sequenced):
    //   prep..qkv      : xh/xl (split x)
    //   fill..qk       : rsorted
    //   node_agg..mlp  : msgH/msgL
    __bf16* xh   = (__bf16*)reg2;
    __bf16* xl   = xh + (size_t)RP * 256;
    int*    rsorted = (int*)reg2;
    __bf16* msgH = (__bf16*)reg2;
    __bf16* msgL = msgH + (size_t)RP * 256;

    dim3 blk(256);
    dim3 edge_grid((M_EDGES + 255) / 256);

    // 1) prep (weights, x split, bias concat, zeroing)
    hipLaunchKernelGGL(prep_kernel, dim3(2048), blk, 0, stream,
                       Wk, Wq, Wv, Wagg, Wff, bk, bq, bv, x,
                       WHq, WLq, WaH, WaL, WfH, WfL, bqkv, xh, xl,
                       counts, cursor, gmax);
    // 2) fused K|Q|V GEMM (XCD-chunked bijective swizzle)
    hipLaunchKernelGGL(gemm_qkv, dim3(2346), blk, 0, stream,
                       xh, xl, WHq, WLq, bqkv, Kbf, Qbuf, Vbf);
    // 3) CSR build (rsorted overlays reg2: xh/xl dead after QKV gemm)
    hipLaunchKernelGGL(hist_kernel, edge_grid, blk, 0, stream, recv, counts);
    hipLaunchKernelGGL(scan_kernel, dim3(1), blk, 0, stream, counts, offsets);
    hipLaunchKernelGGL(fill_kernel, edge_grid, blk, 0, stream, recv, send, offsets,
                       cursor, ssorted, rsorted);
    // 4) edge logits + global max
    hipLaunchKernelGGL(qk_csr_kernel, dim3(1024), blk, 0, stream,
                       ssorted, rsorted, Qbuf, (const unsigned short*)Kbf, qks, gmax);
    // 5) segment softmax + aggregate -> split-bf16 msg (overwrites rsorted region)
    hipLaunchKernelGGL(node_agg_kernel, dim3(2048), blk, 0, stream,
                       offsets, ssorted, qks, (const unsigned short*)Vbf, gmax,
                       msgH, msgL);
    // 6) fused output MLP (hid stays on-chip)
    hipLaunchKernelGGL(mlp_fused, dim3((N_NODES + 127) / 128), blk, 0, stream,
                       msgH, msgL, WaH, WaL, WfH, WfL, bagg, bff, x, out);
}

// Round 9
// 834.094 us; speedup vs baseline: 1.0075x; 1.0075x over previous
//
#include <hip/hip_runtime.h>

#define N_NODES 50000
#define M_EDGES 800000
#define RP 50048  // padded row count for matrix buffers (391 blocks of 128)

typedef __bf16 bf16x8 __attribute__((ext_vector_type(8)));
typedef __bf16 bf16x4 __attribute__((ext_vector_type(4)));
typedef float  f32x4  __attribute__((ext_vector_type(4)));

static __device__ __forceinline__ unsigned enc_ord(float f) {
    unsigned b = __float_as_uint(f);
    return (b & 0x80000000u) ? ~b : (b | 0x80000000u);
}
static __device__ __forceinline__ float dec_ord(unsigned u) {
    unsigned b = (u & 0x80000000u) ? (u ^ 0x80000000u) : ~u;
    return __uint_as_float(b);
}
// bf16 pair packed in a uint: lo = bits[15:0], hi = bits[31:16]
static __device__ __forceinline__ float bflo(unsigned u) { return __uint_as_float(u << 16); }
static __device__ __forceinline__ float bfhi(unsigned u) { return __uint_as_float(u & 0xffff0000u); }
static __device__ __forceinline__ unsigned short bfbits(__bf16 b) {
    unsigned short u; __builtin_memcpy(&u, &b, 2); return u;
}

// PANEL layout: operand plane stored per 128-row block as 8 K-step chunks of
// 8KB, each [4 kslots][128 rows][8 elems] bf16 — EXACTLY the LDS staging order.
// Element index for (row m, k):
static __device__ __forceinline__ size_t PE(int m, int k) {
    return (size_t)(m >> 7) * 32768 + (size_t)(k >> 5) * 4096 +
           (size_t)((k >> 3) & 3) * 1024 + (size_t)(m & 127) * 8 + (k & 7);
}

// async 16B global -> LDS DMA (LDS dest = wave-uniform base + lane*16)
static __device__ __forceinline__ void gload16(const void* g, void* l) {
    __builtin_amdgcn_global_load_lds(
        (const __attribute__((address_space(1))) void*)g,
        (__attribute__((address_space(3))) void*)l, 16, 0, 0);
}

// Panel staging: per step t, 8KB per plane, sequential lane-coalesced reads.
// a0/a1/b0/b1 are char* bases of the 64KB (8-step) panel block for this tile.
static __device__ __forceinline__ void stage_panel(
    const char* a0, const char* a1, const char* b0, const char* b1,
    char* lds0, int buf, int t, int tid) {
    size_t so = (size_t)t * 8192 + (size_t)tid * 16;
    size_t lo = (size_t)buf * 32768 + (size_t)tid * 16;
    gload16(a0 + so, lds0 + lo);
    gload16(a0 + so + 4096, lds0 + lo + 4096);
    gload16(a1 + so, lds0 + 8192 + lo);
    gload16(a1 + so + 4096, lds0 + 8192 + lo + 4096);
    gload16(b0 + so, lds0 + 16384 + lo);
    gload16(b0 + so + 4096, lds0 + 16384 + lo + 4096);
    gload16(b1 + so, lds0 + 24576 + lo);
    gload16(b1 + so + 4096, lds0 + 24576 + lo + 4096);
}

// ---- ONE prep dispatch: weight splits into PANELS (K|Q|V fused 768 rows,
// Wagg/Wff), x split into PANELS, bias concat, counts/cursor/gmax zero.
__global__ __launch_bounds__(256) void prep_kernel(
    const float* __restrict__ Wk, const float* __restrict__ Wq,
    const float* __restrict__ Wv, const float* __restrict__ Wagg,
    const float* __restrict__ Wff,
    const float* __restrict__ bk, const float* __restrict__ bq,
    const float* __restrict__ bv,
    const float* __restrict__ X,
    __bf16* __restrict__ WHq, __bf16* __restrict__ WLq,
    __bf16* __restrict__ WaH, __bf16* __restrict__ WaL,
    __bf16* __restrict__ WfH, __bf16* __restrict__ WfL,
    float* __restrict__ bqkv, __bf16* __restrict__ xh, __bf16* __restrict__ xl,
    int* __restrict__ counts, int* __restrict__ cursor, unsigned* __restrict__ gmax) {
    int gid = blockIdx.x * 256 + threadIdx.x;
    int stride = gridDim.x * 256;
    for (int i = gid; i < 65536; i += stride) {
        int n = i >> 8, k = i & 255;
        size_t src = (size_t)k * 256 + n;
        float v; __bf16 h;
        v = Wk[src];   h = (__bf16)v; WHq[PE(n, k)] = h;
                       WLq[PE(n, k)] = (__bf16)(v - (float)h);
        v = Wq[src];   h = (__bf16)v; WHq[PE(n + 256, k)] = h;
                       WLq[PE(n + 256, k)] = (__bf16)(v - (float)h);
        v = Wv[src];   h = (__bf16)v; WHq[PE(n + 512, k)] = h;
                       WLq[PE(n + 512, k)] = (__bf16)(v - (float)h);
        v = Wagg[src]; h = (__bf16)v; WaH[PE(n, k)] = h;
                       WaL[PE(n, k)] = (__bf16)(v - (float)h);
        v = Wff[src];  h = (__bf16)v; WfH[PE(n, k)] = h;
                       WfL[PE(n, k)] = (__bf16)(v - (float)h);
    }
    const size_t nx = (size_t)N_NODES * 256 / 4;
    for (size_t i = gid; i < nx; i += stride) {
        float4 v = *(const float4*)(X + i * 4);
        int n = (int)(i >> 6), k0 = (int)((i * 4) & 255);
        bf16x4 hh, ll;
        hh[0] = (__bf16)v.x; ll[0] = (__bf16)(v.x - (float)hh[0]);
        hh[1] = (__bf16)v.y; ll[1] = (__bf16)(v.y - (float)hh[1]);
        hh[2] = (__bf16)v.z; ll[2] = (__bf16)(v.z - (float)hh[2]);
        hh[3] = (__bf16)v.w; ll[3] = (__bf16)(v.w - (float)hh[3]);
        size_t idx = PE(n, k0);   // k0 % 4 == 0 -> 4 elems contiguous in panel
        *(bf16x4*)(xh + idx) = hh;
        *(bf16x4*)(xl + idx) = ll;
    }
    for (int i = gid; i < 768; i += stride)
        bqkv[i] = (i < 256) ? bk[i] : ((i < 512) ? bq[i - 256] : bv[i - 512]);
    for (int i = gid; i < N_NODES; i += stride) { counts[i] = 0; cursor[i] = 0; }
    if (gid == 0) *gmax = 0u;
}

// ---- FUSED K|Q|V projection GEMM, panel-staged (lane-coalesced DMA) +
// XCD-chunked bijective swizzle. Outputs row-major Kb(bf16)/Qo(f32)/Vb(bf16).
__global__ __launch_bounds__(256) void gemm_qkv(
    const __bf16* __restrict__ AhP, const __bf16* __restrict__ AlP,
    const __bf16* __restrict__ BhP, const __bf16* __restrict__ BlP,
    const float* __restrict__ bqkv,
    __bf16* __restrict__ Kb, float* __restrict__ Qo, __bf16* __restrict__ Vb) {
    __shared__ __attribute__((aligned(16))) __bf16 sm[2][4][4][128][8];

    // bijective XCD chunking (m204 form), NB = 391*6 = 2346
    const int NB = 2346, q = NB / 8, r = NB % 8;   // 293, 2
    int bid = blockIdx.x;
    int xcd = bid & 7, i0 = bid >> 3;
    int logical = (xcd < r ? xcd * (q + 1) : r * (q + 1) + (xcd - r) * q) + i0;
    int by = logical % 6;
    int bx = logical / 6;
    int row0 = bx * 128;
    int n0   = by * 128;   // fused output col base, 0..640

    int tid  = threadIdx.x;
    int lane = tid & 63, wave = tid >> 6;
    int wm = (wave >> 1) * 64, wn = (wave & 1) * 64;

    f32x4 acc[4][4];
    #pragma unroll
    for (int i = 0; i < 4; i++)
        #pragma unroll
        for (int j = 0; j < 4; j++) acc[i][j] = (f32x4)(0.f);

    const char* a0 = (const char*)AhP + (size_t)bx * 65536;
    const char* a1 = (const char*)AlP + (size_t)bx * 65536;
    const char* b0 = (const char*)BhP + (size_t)by * 65536;
    const char* b1 = (const char*)BlP + (size_t)by * 65536;
    char* lds0 = (char*)&sm[0][0][0][0][0];

    stage_panel(a0, a1, b0, b1, lds0, 0, 0, tid);
    __syncthreads();

    int h = lane >> 4;
    int m_base = wm + (lane & 15);
    int n_base = wn + (lane & 15);

    for (int t = 0; t < 8; t++) {
        int cur = t & 1;
        if (t < 7) stage_panel(a0, a1, b0, b1, lds0, cur ^ 1, t + 1, tid);
        bf16x8 ahf[4], alf[4], bhf[4], blf[4];
        #pragma unroll
        for (int mt = 0; mt < 4; mt++) {
            ahf[mt] = *(const bf16x8*)&sm[cur][0][h][m_base + mt * 16][0];
            alf[mt] = *(const bf16x8*)&sm[cur][1][h][m_base + mt * 16][0];
        }
        #pragma unroll
        for (int nt = 0; nt < 4; nt++) {
            bhf[nt] = *(const bf16x8*)&sm[cur][2][h][n_base + nt * 16][0];
            blf[nt] = *(const bf16x8*)&sm[cur][3][h][n_base + nt * 16][0];
        }
        #pragma unroll
        for (int mt = 0; mt < 4; mt++)
            #pragma unroll
            for (int nt = 0; nt < 4; nt++) {
                acc[mt][nt] = __builtin_amdgcn_mfma_f32_16x16x32_bf16(ahf[mt], bhf[nt], acc[mt][nt], 0, 0, 0);
                acc[mt][nt] = __builtin_amdgcn_mfma_f32_16x16x32_bf16(alf[mt], bhf[nt], acc[mt][nt], 0, 0, 0);
                acc[mt][nt] = __builtin_amdgcn_mfma_f32_16x16x32_bf16(ahf[mt], blf[nt], acc[mt][nt], 0, 0, 0);
            }
        __syncthreads();
    }

    #pragma unroll
    for (int mt = 0; mt < 4; mt++) {
        #pragma unroll
        for (int nt = 0; nt < 4; nt++) {
            int cg = n0 + wn + nt * 16 + (lane & 15);   // fused col 0..767
            #pragma unroll
            for (int rr = 0; rr < 4; rr++) {
                int row = row0 + wm + mt * 16 + (lane >> 4) * 4 + rr;
                if (row < N_NODES) {
                    float v = acc[mt][nt][rr] + bqkv[cg];
                    if (cg < 256)      Kb[(size_t)row * 256 + cg] = (__bf16)v;
                    else if (cg < 512) Qo[(size_t)row * 256 + (cg - 256)] = v;
                    else               Vb[(size_t)row * 256 + (cg - 512)] = (__bf16)v;
                }
            }
        }
    }
}

// ---- CSR build [verbatim, passing] ----
__global__ void hist_kernel(const int* __restrict__ recv, int* __restrict__ counts) {
    int t = blockIdx.x * 256 + threadIdx.x;
    if (t < M_EDGES) atomicAdd(&counts[recv[t]], 1);
}

__global__ void scan_kernel(const int* __restrict__ counts, int* __restrict__ offsets) {
    __shared__ int part[256];
    int t = threadIdx.x;
    const int per = (N_NODES + 255) / 256;
    int start = t * per;
    int end = min(start + per, N_NODES);
    int s = 0;
    for (int i = start; i < end; i++) s += counts[i];
    part[t] = s;
    __syncthreads();
    if (t == 0) {
        int acc = 0;
        for (int i = 0; i < 256; i++) { int v = part[i]; part[i] = acc; acc += v; }
    }
    __syncthreads();
    int acc = part[t];
    for (int i = start; i < end; i++) { offsets[i] = acc; acc += counts[i]; }
    if (end == N_NODES && start < N_NODES) offsets[N_NODES] = acc;
}

__global__ void fill_kernel(const int* __restrict__ recv, const int* __restrict__ send,
                            const int* __restrict__ offsets,
                            int* __restrict__ cursor, int* __restrict__ ssorted,
                            int* __restrict__ rsorted) {
    int t = blockIdx.x * 256 + threadIdx.x;
    if (t < M_EDGES) {
        int r = recv[t];
        int pos = offsets[r] + atomicAdd(&cursor[r], 1);
        ssorted[pos] = send[t];
        rsorted[pos] = r;
    }
}

// ---- edge logits [verbatim, passing: ~121 us @ 1024 blocks]
__global__ __launch_bounds__(256) void qk_csr_kernel(
    const int* __restrict__ ssorted, const int* __restrict__ rsorted,
    const float* __restrict__ Q, const unsigned short* __restrict__ Kb,
    float* __restrict__ qks, unsigned* __restrict__ gmax) {
    int wave_id = (blockIdx.x * 256 + threadIdx.x) >> 6;
    int lane = threadIdx.x & 63;
    int e_slot = lane >> 5;        // which edge of the pair
    int sl = lane & 31;            // 16B chunk within row
    const int nwaves = (gridDim.x * 256) >> 6;
    const int npairs = M_EDGES / 2;
    float wmax = -INFINITY;
    for (int pp = wave_id; pp < npairs; pp += 4 * nwaves) {
        int ep[4]; bool valid[4];
        #pragma unroll
        for (int u = 0; u < 4; u++) {
            int p = pp + u * nwaves;
            valid[u] = p < npairs;
            ep[u] = (valid[u] ? p : pp) * 2 + e_slot;
        }
        int si[4], ri[4];
        #pragma unroll
        for (int u = 0; u < 4; u++) { si[u] = ssorted[ep[u]]; ri[u] = rsorted[ep[u]]; }
        uint4 kv[4]; float4 qa[4], qb[4];
        #pragma unroll
        for (int u = 0; u < 4; u++) {
            kv[u] = *(const uint4*)(Kb + (size_t)si[u] * 256 + sl * 8);
            qa[u] = *(const float4*)(Q + (size_t)ri[u] * 256 + sl * 8);
            qb[u] = *(const float4*)(Q + (size_t)ri[u] * 256 + sl * 8 + 4);
        }
        #pragma unroll
        for (int u = 0; u < 4; u++) {
            float d = qa[u].x * bflo(kv[u].x) + qa[u].y * bfhi(kv[u].x)
                    + qa[u].z * bflo(kv[u].y) + qa[u].w * bfhi(kv[u].y)
                    + qb[u].x * bflo(kv[u].z) + qb[u].y * bfhi(kv[u].z)
                    + qb[u].z * bflo(kv[u].w) + qb[u].w * bfhi(kv[u].w);
            d += __shfl_xor(d, 1);
            d += __shfl_xor(d, 2);
            wmax = fmaxf(wmax, d);
            if ((sl & 3) == 0 && valid[u])
                qks[(size_t)ep[u] * 8 + (sl >> 2)] = d;
        }
    }
    wmax = fmaxf(wmax, __shfl_xor(wmax, 1));
    wmax = fmaxf(wmax, __shfl_xor(wmax, 2));
    wmax = fmaxf(wmax, __shfl_xor(wmax, 4));
    wmax = fmaxf(wmax, __shfl_xor(wmax, 8));
    wmax = fmaxf(wmax, __shfl_xor(wmax, 16));
    wmax = fmaxf(wmax, __shfl_xor(wmax, 32));
    if (lane == 0 && wmax > -INFINITY) atomicMax(gmax, enc_ord(wmax));
}

// ---- node aggregation: emits msg split planes in PANEL layout (same values).
__global__ __launch_bounds__(256) void node_agg_kernel(
    const int* __restrict__ offsets, const int* __restrict__ ssorted,
    const float* __restrict__ qks, const unsigned short* __restrict__ Vb,
    const unsigned* __restrict__ gmax,
    __bf16* __restrict__ msgH, __bf16* __restrict__ msgL) {
    int wave_id = (blockIdx.x * 256 + threadIdx.x) >> 6;
    int lane = threadIdx.x & 63;   // columns lane*4 .. lane*4+3
    int h = lane >> 3;             // head of these columns
    const int nwaves = (gridDim.x * 256) >> 6;
    const int per = (N_NODES + nwaves - 1) / nwaves;
    int n0 = wave_id * per;
    int nend = min(n0 + per, N_NODES);
    float scale = 3.0f / dec_ord(*gmax);
    for (int n = n0; n < nend; n++) {
        int off = offsets[n];
        int deg = offsets[n + 1] - off;
        float sum = 0.f, a0 = 0.f, a1 = 0.f, a2 = 0.f, a3 = 0.f;
        for (int b = 0; b < deg; b += 64) {
            int bn = min(64, deg - b);
            int idxb = ssorted[off + b + min(lane, bn - 1)];
            #define VROW(i) (*(const uint2*)(Vb + \
                (size_t)__shfl(idxb, min((i), bn - 1)) * 256 + lane * 4))
            #define QKL(i) qks[(size_t)(off + b + min((i), bn - 1)) * 8 + h]
            uint2 v0 = VROW(0);
            uint2 v1 = VROW(1);
            float q0 = QKL(0);
            float q1 = QKL(1);
            for (int i = 0; i < bn; i++) {
                uint2 vc = v0; v0 = v1; v1 = VROW(i + 2);
                float qc = q0; q0 = q1; q1 = QKL(i + 2);
                float a = __expf(qc * scale);
                sum += a;
                a0 += a * bflo(vc.x); a1 += a * bfhi(vc.x);
                a2 += a * bflo(vc.y); a3 += a * bfhi(vc.y);
            }
            #undef VROW
            #undef QKL
        }
        float inv = (deg > 0) ? 1.0f / (sum * 5.65685424949238f) : 0.f;  // sqrt(32)
        float r0 = fmaxf(a0 * inv, 0.f), r1 = fmaxf(a1 * inv, 0.f);
        float r2 = fmaxf(a2 * inv, 0.f), r3 = fmaxf(a3 * inv, 0.f);
        bf16x4 hv, lv;
        hv[0] = (__bf16)r0; lv[0] = (__bf16)(r0 - (float)hv[0]);
        hv[1] = (__bf16)r1; lv[1] = (__bf16)(r1 - (float)hv[1]);
        hv[2] = (__bf16)r2; lv[2] = (__bf16)(r2 - (float)hv[2]);
        hv[3] = (__bf16)r3; lv[3] = (__bf16)(r3 - (float)hv[3]);
        size_t idx = PE(n, lane * 4);   // (lane*4)%4==0 -> contiguous 4 elems
        *(bf16x4*)(msgH + idx) = hv;
        *(bf16x4*)(msgL + idx) = lv;
    }
}

// ---- FUSED MLP: out = x + relu(relu(msg@Wagg+bagg)@Wff+bff), one dispatch.
// Panel-staged phases; hid register-resident (never touches HBM); s-loop fully
// unrolled (rule #20). Math order identical to the passing round-8 version.
__global__ __launch_bounds__(256) void mlp_fused(
    const __bf16* __restrict__ msgHP, const __bf16* __restrict__ msgLP,
    const __bf16* __restrict__ WaHP, const __bf16* __restrict__ WaLP,
    const __bf16* __restrict__ WfHP, const __bf16* __restrict__ WfLP,
    const float* __restrict__ bagg, const float* __restrict__ bff,
    const float* __restrict__ x, float* __restrict__ out) {
    __shared__ __attribute__((aligned(16))) __bf16 sm[2][4][4][128][8];   // 64 KB

    int row0 = blockIdx.x * 128;
    int bxp  = blockIdx.x;
    int tid  = threadIdx.x;
    int lane = tid & 63, wave = tid >> 6;
    int wm = (wave >> 1) * 64, wn = (wave & 1) * 64;
    char* lds0 = (char*)&sm[0][0][0][0][0];
    int h = lane >> 4;
    int m_base = wm + (lane & 15);
    int n_base = wn + (lane & 15);

    // ---- phase A: hid = relu(msg @ Wagg + bagg), two col-halves
    f32x4 acc1[2][4][4];
    #pragma unroll
    for (int nh = 0; nh < 2; nh++)
        #pragma unroll
        for (int i = 0; i < 4; i++)
            #pragma unroll
            for (int j = 0; j < 4; j++) acc1[nh][i][j] = (f32x4)(0.f);

    const char* a0 = (const char*)msgHP + (size_t)bxp * 65536;
    const char* a1 = (const char*)msgLP + (size_t)bxp * 65536;

    #pragma unroll
    for (int nh = 0; nh < 2; nh++) {
        const char* b0 = (const char*)WaHP + (size_t)nh * 65536;
        const char* b1 = (const char*)WaLP + (size_t)nh * 65536;
        stage_panel(a0, a1, b0, b1, lds0, 0, 0, tid);
        __syncthreads();
        for (int t = 0; t < 8; t++) {
            int cur = t & 1;
            if (t < 7) stage_panel(a0, a1, b0, b1, lds0, cur ^ 1, t + 1, tid);
            bf16x8 ahf[4], alf[4], bhf[4], blf[4];
            #pragma unroll
            for (int mt = 0; mt < 4; mt++) {
                ahf[mt] = *(const bf16x8*)&sm[cur][0][h][m_base + mt * 16][0];
                alf[mt] = *(const bf16x8*)&sm[cur][1][h][m_base + mt * 16][0];
            }
            #pragma unroll
            for (int nt = 0; nt < 4; nt++) {
                bhf[nt] = *(const bf16x8*)&sm[cur][2][h][n_base + nt * 16][0];
                blf[nt] = *(const bf16x8*)&sm[cur][3][h][n_base + nt * 16][0];
            }
            #pragma unroll
            for (int mt = 0; mt < 4; mt++)
                #pragma unroll
                for (int nt = 0; nt < 4; nt++) {
                    acc1[nh][mt][nt] = __builtin_amdgcn_mfma_f32_16x16x32_bf16(ahf[mt], bhf[nt], acc1[nh][mt][nt], 0, 0, 0);
                    acc1[nh][mt][nt] = __builtin_amdgcn_mfma_f32_16x16x32_bf16(alf[mt], bhf[nt], acc1[nh][mt][nt], 0, 0, 0);
                    acc1[nh][mt][nt] = __builtin_amdgcn_mfma_f32_16x16x32_bf16(ahf[mt], blf[nt], acc1[nh][mt][nt], 0, 0, 0);
                }
            __syncthreads();
        }
    }

    // bias + relu + split-bf16, packed H | L<<16 per element
    unsigned hidp[2][4][4][4];
    #pragma unroll
    for (int nh = 0; nh < 2; nh++)
        #pragma unroll
        for (int mt = 0; mt < 4; mt++)
            #pragma unroll
            for (int nt = 0; nt < 4; nt++)
                #pragma unroll
                for (int rr = 0; rr < 4; rr++) {
                    int col = nh * 128 + wn + nt * 16 + (lane & 15);
                    float v = acc1[nh][mt][nt][rr] + bagg[col];
                    v = fmaxf(v, 0.f);
                    __bf16 hh = (__bf16)v;
                    __bf16 hl = (__bf16)(v - (float)hh);
                    hidp[nh][mt][nt][rr] =
                        (unsigned)bfbits(hh) | ((unsigned)bfbits(hl) << 16);
                }

    // ---- phase B: out = x + relu(hid @ Wff + bff), per k-slot LDS exchange
    unsigned short* chunkw = (unsigned short*)lds0;              // [2][4][128][8]
    const __bf16*   chunkb = (const __bf16*)lds0;
    char*           b2c    = lds0 + 16384;                       // Wff H|L planes
    const __bf16*   b2b    = (const __bf16*)(lds0 + 16384);

    for (int oh = 0; oh < 2; oh++) {
        const char* f0 = (const char*)WfHP + (size_t)oh * 65536;
        const char* f1 = (const char*)WfLP + (size_t)oh * 65536;
        f32x4 acc2[4][4];
        #pragma unroll
        for (int i = 0; i < 4; i++)
            #pragma unroll
            for (int j = 0; j < 4; j++) acc2[i][j] = (f32x4)(0.f);

        #pragma unroll
        for (int s = 0; s < 8; s++) {
            __syncthreads();   // previous iteration's LDS reads done
            // (a) owning waves write hid slot s (32 cols) into chunk
            int nh = s >> 2, sq = s & 3;   // compile-time (s unrolled)
            if (wn == ((sq >= 2) ? 64 : 0)) {
                int nt0 = (sq & 1) * 2;
                #pragma unroll
                for (int mt = 0; mt < 4; mt++)
                    #pragma unroll
                    for (int j = 0; j < 2; j++) {
                        int nt = nt0 + j;
                        int kc = (wn + nt * 16 + (lane & 15)) - 32 * sq;  // 0..31
                        int ks = kc >> 3, e = kc & 7;
                        #pragma unroll
                        for (int rr = 0; rr < 4; rr++) {
                            int row = wm + mt * 16 + (lane >> 4) * 4 + rr;
                            unsigned u = hidp[nh][mt][nt][rr];
                            chunkw[(size_t)ks * 1024 + row * 8 + e] =
                                (unsigned short)(u & 0xffffu);
                            chunkw[(size_t)(4 + ks) * 1024 + row * 8 + e] =
                                (unsigned short)(u >> 16);
                        }
                    }
            }
            // (b) stage Wff panel step s (lane-coalesced)
            {
                size_t so = (size_t)s * 8192 + (size_t)tid * 16;
                size_t lo = (size_t)tid * 16;
                gload16(f0 + so, b2c + lo);
                gload16(f0 + so + 4096, b2c + lo + 4096);
                gload16(f1 + so, b2c + 8192 + lo);
                gload16(f1 + so + 4096, b2c + 8192 + lo + 4096);
            }
            __syncthreads();   // ds-writes + DMA drained
            // (c) MFMA
            bf16x8 a2h[4], a2l[4], b2h[4], b2l[4];
            #pragma unroll
            for (int mt = 0; mt < 4; mt++) {
                a2h[mt] = *(const bf16x8*)&chunkb[(size_t)h * 1024 + (m_base + mt * 16) * 8];
                a2l[mt] = *(const bf16x8*)&chunkb[(size_t)(4 + h) * 1024 + (m_base + mt * 16) * 8];
            }
            #pragma unroll
            for (int nt = 0; nt < 4; nt++) {
                b2h[nt] = *(const bf16x8*)&b2b[(size_t)h * 1024 + (n_base + nt * 16) * 8];
                b2l[nt] = *(const bf16x8*)&b2b[(size_t)(4 + h) * 1024 + (n_base + nt * 16) * 8];
            }
            #pragma unroll
            for (int mt = 0; mt < 4; mt++)
                #pragma unroll
                for (int nt = 0; nt < 4; nt++) {
                    acc2[mt][nt] = __builtin_amdgcn_mfma_f32_16x16x32_bf16(a2h[mt], b2h[nt], acc2[mt][nt], 0, 0, 0);
                    acc2[mt][nt] = __builtin_amdgcn_mfma_f32_16x16x32_bf16(a2l[mt], b2h[nt], acc2[mt][nt], 0, 0, 0);
                    acc2[mt][nt] = __builtin_amdgcn_mfma_f32_16x16x32_bf16(a2h[mt], b2l[nt], acc2[mt][nt], 0, 0, 0);
                }
        }
        // epilogue for this out col-half
        #pragma unroll
        for (int mt = 0; mt < 4; mt++)
            #pragma unroll
            for (int nt = 0; nt < 4; nt++) {
                int oc = oh * 128 + wn + nt * 16 + (lane & 15);
                #pragma unroll
                for (int rr = 0; rr < 4; rr++) {
                    int row = row0 + wm + mt * 16 + (lane >> 4) * 4 + rr;
                    if (row < N_NODES) {
                        float v = acc2[mt][nt][rr] + bff[oc];
                        v = fmaxf(v, 0.f);
                        size_t idx = (size_t)row * 256 + oc;
                        out[idx] = v + x[idx];
                    }
                }
            }
    }
}

extern "C" void kernel_launch(void* const* d_in, const int* in_sizes, int n_in,
                              void* d_out, int out_size, void* d_ws, size_t ws_size,
                              hipStream_t stream) {
    const float* x    = (const float*)d_in[0];
    const int*   edge = (const int*)d_in[1];
    const int*   recv = edge;
    const int*   send = edge + M_EDGES;
    const float* Wk   = (const float*)d_in[2];
    const float* bk   = (const float*)d_in[3];
    const float* Wq   = (const float*)d_in[4];
    const float* bq   = (const float*)d_in[5];
    const float* Wv   = (const float*)d_in[6];
    const float* bv   = (const float*)d_in[7];
    const float* Wagg = (const float*)d_in[8];
    const float* bagg = (const float*)d_in[9];
    const float* Wff  = (const float*)d_in[10];
    const float* bff  = (const float*)d_in[11];
    float* out = (float*)d_out;

    float*  Qbuf  = (float*)d_ws;                       // RP*256 f32 (row-major)
    float*  reg2  = Qbuf + (size_t)RP * 256;            // RP*256 f32 multi-use
    float*  qks   = reg2 + (size_t)RP * 256;
    __bf16* Kbf   = (__bf16*)(qks + (size_t)M_EDGES * 8);
    __bf16* Vbf   = Kbf + (size_t)RP * 256;
    int* counts   = (int*)(Vbf + (size_t)RP * 256);
    int* cursor   = counts + N_NODES;
    int* offsets  = cursor + N_NODES;
    int* ssorted  = offsets + N_NODES + 1;
    unsigned* gmax = (unsigned*)(ssorted + M_EDGES);
    __bf16* wt    = (__bf16*)(gmax + 1);
    __bf16* WHq = wt;                    // fused QKV panel, 6 blocks
    __bf16* WLq = wt + 3 * 65536;
    __bf16* WaH = wt + 6 * 65536;  __bf16* WaL = wt + 7 * 65536;
    __bf16* WfH = wt + 8 * 65536;  __bf16* WfL = wt + 9 * 65536;
    float* bqkv = (float*)(wt + 10 * 65536);   // [768]
    // reg2 overlays (strictly sequenced):
    //   prep..qkv      : xh/xl (panel split x)
    //   fill..qk       : rsorted
    //   node_agg..mlp  : msgH/msgL (panels)
    __bf16* xh   = (__bf16*)reg2;
    __bf16* xl   = xh + (size_t)RP * 256;
    int*    rsorted = (int*)reg2;
    __bf16* msgH = (__bf16*)reg2;
    __bf16* msgL = msgH + (size_t)RP * 256;

    dim3 blk(256);
    dim3 edge_grid((M_EDGES + 255) / 256);

    // 1) prep (panel weights, panel x split, bias concat, zeroing)
    hipLaunchKernelGGL(prep_kernel, dim3(2048), blk, 0, stream,
                       Wk, Wq, Wv, Wagg, Wff, bk, bq, bv, x,
                       WHq, WLq, WaH, WaL, WfH, WfL, bqkv, xh, xl,
                       counts, cursor, gmax);
    // 2) fused K|Q|V GEMM (panel-staged + XCD swizzle)
    hipLaunchKernelGGL(gemm_qkv, dim3(2346), blk, 0, stream,
                       xh, xl, WHq, WLq, bqkv, Kbf, Qbuf, Vbf);
    // 3) CSR build (rsorted overlays reg2: xh/xl dead after QKV gemm)
    hipLaunchKernelGGL(hist_kernel, edge_grid, blk, 0, stream, recv, counts);
    hipLaunchKernelGGL(scan_kernel, dim3(1), blk, 0, stream, counts, offsets);
    hipLaunchKernelGGL(fill_kernel, edge_grid, blk, 0, stream, recv, send, offsets,
                       cursor, ssorted, rsorted);
    // 4) edge logits + global max
    hipLaunchKernelGGL(qk_csr_kernel, dim3(1024), blk, 0, stream,
                       ssorted, rsorted, Qbuf, (const unsigned short*)Kbf, qks, gmax);
    // 5) segment softmax + aggregate -> panel split-bf16 msg
    hipLaunchKernelGGL(node_agg_kernel, dim3(2048), blk, 0, stream,
                       offsets, ssorted, qks, (const unsigned short*)Vbf, gmax,
                       msgH, msgL);
    // 6) fused output MLP (panel-staged; hid stays on-chip)
    hipLaunchKernelGGL(mlp_fused, dim3((N_NODES + 127) / 128), blk, 0, stream,
                       msgH, msgL, WaH, WaL, WfH, WfL, bagg, bff, x, out);
}

// Round 10
// 825.541 us; speedup vs baseline: 1.0179x; 1.0104x over previous
//
#include <hip/hip_runtime.h>

#define N_NODES 50000
#define M_EDGES 800000
#define RP 50048  // padded row count for matrix buffers (391 blocks of 128)

typedef __bf16 bf16x8 __attribute__((ext_vector_type(8)));
typedef __bf16 bf16x4 __attribute__((ext_vector_type(4)));
typedef float  f32x4  __attribute__((ext_vector_type(4)));

static __device__ __forceinline__ unsigned enc_ord(float f) {
    unsigned b = __float_as_uint(f);
    return (b & 0x80000000u) ? ~b : (b | 0x80000000u);
}
static __device__ __forceinline__ float dec_ord(unsigned u) {
    unsigned b = (u & 0x80000000u) ? (u ^ 0x80000000u) : ~u;
    return __uint_as_float(b);
}
// bf16 pair packed in a uint: lo = bits[15:0], hi = bits[31:16]
static __device__ __forceinline__ float bflo(unsigned u) { return __uint_as_float(u << 16); }
static __device__ __forceinline__ float bfhi(unsigned u) { return __uint_as_float(u & 0xffff0000u); }
static __device__ __forceinline__ unsigned short bfbits(__bf16 b) {
    unsigned short u; __builtin_memcpy(&u, &b, 2); return u;
}

// PANEL layout: operand plane stored per 128-row block as 8 K-step chunks of
// 8KB, each [4 kslots][128 rows][8 elems] bf16 — EXACTLY the LDS staging order.
static __device__ __forceinline__ size_t PE(int m, int k) {
    return (size_t)(m >> 7) * 32768 + (size_t)(k >> 5) * 4096 +
           (size_t)((k >> 3) & 3) * 1024 + (size_t)(m & 127) * 8 + (k & 7);
}

// async 16B global -> LDS DMA (LDS dest = wave-uniform base + lane*16)
static __device__ __forceinline__ void gload16(const void* g, void* l) {
    __builtin_amdgcn_global_load_lds(
        (const __attribute__((address_space(1))) void*)g,
        (__attribute__((address_space(3))) void*)l, 16, 0, 0);
}

// Panel staging: per step t, 8KB per plane, sequential lane-coalesced reads.
static __device__ __forceinline__ void stage_panel(
    const char* a0, const char* a1, const char* b0, const char* b1,
    char* lds0, int buf, int t, int tid) {
    size_t so = (size_t)t * 8192 + (size_t)tid * 16;
    size_t lo = (size_t)buf * 32768 + (size_t)tid * 16;
    gload16(a0 + so, lds0 + lo);
    gload16(a0 + so + 4096, lds0 + lo + 4096);
    gload16(a1 + so, lds0 + 8192 + lo);
    gload16(a1 + so + 4096, lds0 + 8192 + lo + 4096);
    gload16(b0 + so, lds0 + 16384 + lo);
    gload16(b0 + so + 4096, lds0 + 16384 + lo + 4096);
    gload16(b1 + so, lds0 + 24576 + lo);
    gload16(b1 + so + 4096, lds0 + 24576 + lo + 4096);
}

// ---- ONE prep dispatch [verbatim, passing]
__global__ __launch_bounds__(256) void prep_kernel(
    const float* __restrict__ Wk, const float* __restrict__ Wq,
    const float* __restrict__ Wv, const float* __restrict__ Wagg,
    const float* __restrict__ Wff,
    const float* __restrict__ bk, const float* __restrict__ bq,
    const float* __restrict__ bv,
    const float* __restrict__ X,
    __bf16* __restrict__ WHq, __bf16* __restrict__ WLq,
    __bf16* __restrict__ WaH, __bf16* __restrict__ WaL,
    __bf16* __restrict__ WfH, __bf16* __restrict__ WfL,
    float* __restrict__ bqkv, __bf16* __restrict__ xh, __bf16* __restrict__ xl,
    int* __restrict__ counts, int* __restrict__ cursor, unsigned* __restrict__ gmax) {
    int gid = blockIdx.x * 256 + threadIdx.x;
    int stride = gridDim.x * 256;
    for (int i = gid; i < 65536; i += stride) {
        int n = i >> 8, k = i & 255;
        size_t src = (size_t)k * 256 + n;
        float v; __bf16 h;
        v = Wk[src];   h = (__bf16)v; WHq[PE(n, k)] = h;
                       WLq[PE(n, k)] = (__bf16)(v - (float)h);
        v = Wq[src];   h = (__bf16)v; WHq[PE(n + 256, k)] = h;
                       WLq[PE(n + 256, k)] = (__bf16)(v - (float)h);
        v = Wv[src];   h = (__bf16)v; WHq[PE(n + 512, k)] = h;
                       WLq[PE(n + 512, k)] = (__bf16)(v - (float)h);
        v = Wagg[src]; h = (__bf16)v; WaH[PE(n, k)] = h;
                       WaL[PE(n, k)] = (__bf16)(v - (float)h);
        v = Wff[src];  h = (__bf16)v; WfH[PE(n, k)] = h;
                       WfL[PE(n, k)] = (__bf16)(v - (float)h);
    }
    const size_t nx = (size_t)N_NODES * 256 / 4;
    for (size_t i = gid; i < nx; i += stride) {
        float4 v = *(const float4*)(X + i * 4);
        int n = (int)(i >> 6), k0 = (int)((i * 4) & 255);
        bf16x4 hh, ll;
        hh[0] = (__bf16)v.x; ll[0] = (__bf16)(v.x - (float)hh[0]);
        hh[1] = (__bf16)v.y; ll[1] = (__bf16)(v.y - (float)hh[1]);
        hh[2] = (__bf16)v.z; ll[2] = (__bf16)(v.z - (float)hh[2]);
        hh[3] = (__bf16)v.w; ll[3] = (__bf16)(v.w - (float)hh[3]);
        size_t idx = PE(n, k0);
        *(bf16x4*)(xh + idx) = hh;
        *(bf16x4*)(xl + idx) = ll;
    }
    for (int i = gid; i < 768; i += stride)
        bqkv[i] = (i < 256) ? bk[i] : ((i < 512) ? bq[i - 256] : bv[i - 512]);
    for (int i = gid; i < N_NODES; i += stride) { counts[i] = 0; cursor[i] = 0; }
    if (gid == 0) *gmax = 0u;
}

// ---- FUSED K|Q|V projection GEMM [verbatim, passing; control dispatch]
__global__ __launch_bounds__(256) void gemm_qkv(
    const __bf16* __restrict__ AhP, const __bf16* __restrict__ AlP,
    const __bf16* __restrict__ BhP, const __bf16* __restrict__ BlP,
    const float* __restrict__ bqkv,
    __bf16* __restrict__ Kb, float* __restrict__ Qo, __bf16* __restrict__ Vb) {
    __shared__ __attribute__((aligned(16))) __bf16 sm[2][4][4][128][8];

    const int NB = 2346, q = NB / 8, r = NB % 8;   // 293, 2
    int bid = blockIdx.x;
    int xcd = bid & 7, i0 = bid >> 3;
    int logical = (xcd < r ? xcd * (q + 1) : r * (q + 1) + (xcd - r) * q) + i0;
    int by = logical % 6;
    int bx = logical / 6;
    int row0 = bx * 128;
    int n0   = by * 128;

    int tid  = threadIdx.x;
    int lane = tid & 63, wave = tid >> 6;
    int wm = (wave >> 1) * 64, wn = (wave & 1) * 64;

    f32x4 acc[4][4];
    #pragma unroll
    for (int i = 0; i < 4; i++)
        #pragma unroll
        for (int j = 0; j < 4; j++) acc[i][j] = (f32x4)(0.f);

    const char* a0 = (const char*)AhP + (size_t)bx * 65536;
    const char* a1 = (const char*)AlP + (size_t)bx * 65536;
    const char* b0 = (const char*)BhP + (size_t)by * 65536;
    const char* b1 = (const char*)BlP + (size_t)by * 65536;
    char* lds0 = (char*)&sm[0][0][0][0][0];

    stage_panel(a0, a1, b0, b1, lds0, 0, 0, tid);
    __syncthreads();

    int h = lane >> 4;
    int m_base = wm + (lane & 15);
    int n_base = wn + (lane & 15);

    for (int t = 0; t < 8; t++) {
        int cur = t & 1;
        if (t < 7) stage_panel(a0, a1, b0, b1, lds0, cur ^ 1, t + 1, tid);
        bf16x8 ahf[4], alf[4], bhf[4], blf[4];
        #pragma unroll
        for (int mt = 0; mt < 4; mt++) {
            ahf[mt] = *(const bf16x8*)&sm[cur][0][h][m_base + mt * 16][0];
            alf[mt] = *(const bf16x8*)&sm[cur][1][h][m_base + mt * 16][0];
        }
        #pragma unroll
        for (int nt = 0; nt < 4; nt++) {
            bhf[nt] = *(const bf16x8*)&sm[cur][2][h][n_base + nt * 16][0];
            blf[nt] = *(const bf16x8*)&sm[cur][3][h][n_base + nt * 16][0];
        }
        #pragma unroll
        for (int mt = 0; mt < 4; mt++)
            #pragma unroll
            for (int nt = 0; nt < 4; nt++) {
                acc[mt][nt] = __builtin_amdgcn_mfma_f32_16x16x32_bf16(ahf[mt], bhf[nt], acc[mt][nt], 0, 0, 0);
                acc[mt][nt] = __builtin_amdgcn_mfma_f32_16x16x32_bf16(alf[mt], bhf[nt], acc[mt][nt], 0, 0, 0);
                acc[mt][nt] = __builtin_amdgcn_mfma_f32_16x16x32_bf16(ahf[mt], blf[nt], acc[mt][nt], 0, 0, 0);
            }
        __syncthreads();
    }

    #pragma unroll
    for (int mt = 0; mt < 4; mt++) {
        #pragma unroll
        for (int nt = 0; nt < 4; nt++) {
            int cg = n0 + wn + nt * 16 + (lane & 15);
            #pragma unroll
            for (int rr = 0; rr < 4; rr++) {
                int row = row0 + wm + mt * 16 + (lane >> 4) * 4 + rr;
                if (row < N_NODES) {
                    float v = acc[mt][nt][rr] + bqkv[cg];
                    if (cg < 256)      Kb[(size_t)row * 256 + cg] = (__bf16)v;
                    else if (cg < 512) Qo[(size_t)row * 256 + (cg - 256)] = v;
                    else               Vb[(size_t)row * 256 + (cg - 512)] = (__bf16)v;
                }
            }
        }
    }
}

// ---- CSR build [verbatim, passing] ----
__global__ void hist_kernel(const int* __restrict__ recv, int* __restrict__ counts) {
    int t = blockIdx.x * 256 + threadIdx.x;
    if (t < M_EDGES) atomicAdd(&counts[recv[t]], 1);
}

__global__ void scan_kernel(const int* __restrict__ counts, int* __restrict__ offsets) {
    __shared__ int part[256];
    int t = threadIdx.x;
    const int per = (N_NODES + 255) / 256;
    int start = t * per;
    int end = min(start + per, N_NODES);
    int s = 0;
    for (int i = start; i < end; i++) s += counts[i];
    part[t] = s;
    __syncthreads();
    if (t == 0) {
        int acc = 0;
        for (int i = 0; i < 256; i++) { int v = part[i]; part[i] = acc; acc += v; }
    }
    __syncthreads();
    int acc = part[t];
    for (int i = start; i < end; i++) { offsets[i] = acc; acc += counts[i]; }
    if (end == N_NODES && start < N_NODES) offsets[N_NODES] = acc;
}

__global__ void fill_kernel(const int* __restrict__ recv, const int* __restrict__ send,
                            const int* __restrict__ offsets,
                            int* __restrict__ cursor, int* __restrict__ ssorted,
                            int* __restrict__ rsorted) {
    int t = blockIdx.x * 256 + threadIdx.x;
    if (t < M_EDGES) {
        int r = recv[t];
        int pos = offsets[r] + atomicAdd(&cursor[r], 1);
        ssorted[pos] = send[t];
        rsorted[pos] = r;
    }
}

// ---- edge logits [verbatim, passing: ~121 us @ 1024 blocks]
__global__ __launch_bounds__(256) void qk_csr_kernel(
    const int* __restrict__ ssorted, const int* __restrict__ rsorted,
    const float* __restrict__ Q, const unsigned short* __restrict__ Kb,
    float* __restrict__ qks, unsigned* __restrict__ gmax) {
    int wave_id = (blockIdx.x * 256 + threadIdx.x) >> 6;
    int lane = threadIdx.x & 63;
    int e_slot = lane >> 5;
    int sl = lane & 31;
    const int nwaves = (gridDim.x * 256) >> 6;
    const int npairs = M_EDGES / 2;
    float wmax = -INFINITY;
    for (int pp = wave_id; pp < npairs; pp += 4 * nwaves) {
        int ep[4]; bool valid[4];
        #pragma unroll
        for (int u = 0; u < 4; u++) {
            int p = pp + u * nwaves;
            valid[u] = p < npairs;
            ep[u] = (valid[u] ? p : pp) * 2 + e_slot;
        }
        int si[4], ri[4];
        #pragma unroll
        for (int u = 0; u < 4; u++) { si[u] = ssorted[ep[u]]; ri[u] = rsorted[ep[u]]; }
        uint4 kv[4]; float4 qa[4], qb[4];
        #pragma unroll
        for (int u = 0; u < 4; u++) {
            kv[u] = *(const uint4*)(Kb + (size_t)si[u] * 256 + sl * 8);
            qa[u] = *(const float4*)(Q + (size_t)ri[u] * 256 + sl * 8);
            qb[u] = *(const float4*)(Q + (size_t)ri[u] * 256 + sl * 8 + 4);
        }
        #pragma unroll
        for (int u = 0; u < 4; u++) {
            float d = qa[u].x * bflo(kv[u].x) + qa[u].y * bfhi(kv[u].x)
                    + qa[u].z * bflo(kv[u].y) + qa[u].w * bfhi(kv[u].y)
                    + qb[u].x * bflo(kv[u].z) + qb[u].y * bfhi(kv[u].z)
                    + qb[u].z * bflo(kv[u].w) + qb[u].w * bfhi(kv[u].w);
            d += __shfl_xor(d, 1);
            d += __shfl_xor(d, 2);
            wmax = fmaxf(wmax, d);
            if ((sl & 3) == 0 && valid[u])
                qks[(size_t)ep[u] * 8 + (sl >> 2)] = d;
        }
    }
    wmax = fmaxf(wmax, __shfl_xor(wmax, 1));
    wmax = fmaxf(wmax, __shfl_xor(wmax, 2));
    wmax = fmaxf(wmax, __shfl_xor(wmax, 4));
    wmax = fmaxf(wmax, __shfl_xor(wmax, 8));
    wmax = fmaxf(wmax, __shfl_xor(wmax, 16));
    wmax = fmaxf(wmax, __shfl_xor(wmax, 32));
    if (lane == 0 && wmax > -INFINITY) atomicMax(gmax, enc_ord(wmax));
}

// ---- node aggregation [verbatim, passing]
__global__ __launch_bounds__(256) void node_agg_kernel(
    const int* __restrict__ offsets, const int* __restrict__ ssorted,
    const float* __restrict__ qks, const unsigned short* __restrict__ Vb,
    const unsigned* __restrict__ gmax,
    __bf16* __restrict__ msgH, __bf16* __restrict__ msgL) {
    int wave_id = (blockIdx.x * 256 + threadIdx.x) >> 6;
    int lane = threadIdx.x & 63;
    int h = lane >> 3;
    const int nwaves = (gridDim.x * 256) >> 6;
    const int per = (N_NODES + nwaves - 1) / nwaves;
    int n0 = wave_id * per;
    int nend = min(n0 + per, N_NODES);
    float scale = 3.0f / dec_ord(*gmax);
    for (int n = n0; n < nend; n++) {
        int off = offsets[n];
        int deg = offsets[n + 1] - off;
        float sum = 0.f, a0 = 0.f, a1 = 0.f, a2 = 0.f, a3 = 0.f;
        for (int b = 0; b < deg; b += 64) {
            int bn = min(64, deg - b);
            int idxb = ssorted[off + b + min(lane, bn - 1)];
            #define VROW(i) (*(const uint2*)(Vb + \
                (size_t)__shfl(idxb, min((i), bn - 1)) * 256 + lane * 4))
            #define QKL(i) qks[(size_t)(off + b + min((i), bn - 1)) * 8 + h]
            uint2 v0 = VROW(0);
            uint2 v1 = VROW(1);
            float q0 = QKL(0);
            float q1 = QKL(1);
            for (int i = 0; i < bn; i++) {
                uint2 vc = v0; v0 = v1; v1 = VROW(i + 2);
                float qc = q0; q0 = q1; q1 = QKL(i + 2);
                float a = __expf(qc * scale);
                sum += a;
                a0 += a * bflo(vc.x); a1 += a * bfhi(vc.x);
                a2 += a * bflo(vc.y); a3 += a * bfhi(vc.y);
            }
            #undef VROW
            #undef QKL
        }
        float inv = (deg > 0) ? 1.0f / (sum * 5.65685424949238f) : 0.f;  // sqrt(32)
        float r0 = fmaxf(a0 * inv, 0.f), r1 = fmaxf(a1 * inv, 0.f);
        float r2 = fmaxf(a2 * inv, 0.f), r3 = fmaxf(a3 * inv, 0.f);
        bf16x4 hv, lv;
        hv[0] = (__bf16)r0; lv[0] = (__bf16)(r0 - (float)hv[0]);
        hv[1] = (__bf16)r1; lv[1] = (__bf16)(r1 - (float)hv[1]);
        hv[2] = (__bf16)r2; lv[2] = (__bf16)(r2 - (float)hv[2]);
        hv[3] = (__bf16)r3; lv[3] = (__bf16)(r3 - (float)hv[3]);
        size_t idx = PE(n, lane * 4);
        *(bf16x4*)(msgH + idx) = hv;
        *(bf16x4*)(msgL + idx) = lv;
    }
}

// ---- FUSED MLP, BARRIER-MINIMAL: A (msg) staged half-K into a single 64KB
// LDS buffer (2 DMA-drains total); B (Wagg/Wff, L2-hot) read directly from
// global as panel fragments; within a half the 4 K-steps are barrier-free.
// Phase B: hid exchanged per k-half (ds_write barriers only, no DMA drains).
// Accumulation order per accumulator unchanged (k ascending, hh/lh/hl)
// -> bit-identical to the passing round-9 version.
__global__ __launch_bounds__(256) void mlp_fused(
    const __bf16* __restrict__ msgHP, const __bf16* __restrict__ msgLP,
    const __bf16* __restrict__ WaHP, const __bf16* __restrict__ WaLP,
    const __bf16* __restrict__ WfHP, const __bf16* __restrict__ WfLP,
    const float* __restrict__ bagg, const float* __restrict__ bff,
    const float* __restrict__ x, float* __restrict__ out) {
    __shared__ __attribute__((aligned(16))) __bf16 sm[32768];   // 64 KB

    int row0 = blockIdx.x * 128;
    int tid  = threadIdx.x;
    int lane = tid & 63, wave = tid >> 6;
    int wm = (wave >> 1) * 64, wn = (wave & 1) * 64;
    char* lds0 = (char*)sm;
    int h = lane >> 4;
    int m_base = wm + (lane & 15);
    int n_base = wn + (lane & 15);

    const char* a0 = (const char*)msgHP + (size_t)blockIdx.x * 65536;
    const char* a1 = (const char*)msgLP + (size_t)blockIdx.x * 65536;

    // ---- phase A: hid = relu(msg @ Wagg + bagg)
    f32x4 acc1[2][4][4];
    #pragma unroll
    for (int nh = 0; nh < 2; nh++)
        #pragma unroll
        for (int i = 0; i < 4; i++)
            #pragma unroll
            for (int j = 0; j < 4; j++) acc1[nh][i][j] = (f32x4)(0.f);

    // stage K-half 0 (global steps 0-3): H plane [0,32K), L plane [32K,64K)
    #pragma unroll
    for (int tl = 0; tl < 4; tl++) {
        size_t so = (size_t)tl * 8192 + (size_t)tid * 16;
        gload16(a0 + so, lds0 + so);
        gload16(a0 + so + 4096, lds0 + so + 4096);
        gload16(a1 + so, lds0 + 32768 + so);
        gload16(a1 + so + 4096, lds0 + 32768 + so + 4096);
    }
    __syncthreads();   // DMA drain #1

    #pragma unroll
    for (int hf = 0; hf < 2; hf++) {
        // compute steps hf*4 .. hf*4+3 for BOTH nh (separate accumulators;
        // k ascends within each acc1[nh] -> FP order unchanged)
        #pragma unroll
        for (int nh = 0; nh < 2; nh++) {
            const __bf16* wb0 = WaHP + (size_t)nh * 32768;
            const __bf16* wb1 = WaLP + (size_t)nh * 32768;
            #pragma unroll
            for (int tl = 0; tl < 4; tl++) {
                int t = hf * 4 + tl;
                const __bf16* lA = (const __bf16*)lds0;
                bf16x8 ahf[4], alf[4], bhf[4], blf[4];
                #pragma unroll
                for (int mt = 0; mt < 4; mt++) {
                    size_t ai = (size_t)tl * 4096 + (size_t)h * 1024 + (size_t)(m_base + mt * 16) * 8;
                    ahf[mt] = *(const bf16x8*)&lA[ai];
                    alf[mt] = *(const bf16x8*)&lA[16384 + ai];
                }
                #pragma unroll
                for (int nt = 0; nt < 4; nt++) {
                    size_t bi = (size_t)t * 4096 + (size_t)h * 1024 + (size_t)(n_base + nt * 16) * 8;
                    bhf[nt] = *(const bf16x8*)(wb0 + bi);
                    blf[nt] = *(const bf16x8*)(wb1 + bi);
                }
                #pragma unroll
                for (int mt = 0; mt < 4; mt++)
                    #pragma unroll
                    for (int nt = 0; nt < 4; nt++) {
                        acc1[nh][mt][nt] = __builtin_amdgcn_mfma_f32_16x16x32_bf16(ahf[mt], bhf[nt], acc1[nh][mt][nt], 0, 0, 0);
                        acc1[nh][mt][nt] = __builtin_amdgcn_mfma_f32_16x16x32_bf16(alf[mt], bhf[nt], acc1[nh][mt][nt], 0, 0, 0);
                        acc1[nh][mt][nt] = __builtin_amdgcn_mfma_f32_16x16x32_bf16(ahf[mt], blf[nt], acc1[nh][mt][nt], 0, 0, 0);
                    }
            }
        }
        if (hf == 0) {
            __syncthreads();   // all reads of half 0 done
            #pragma unroll
            for (int tl = 0; tl < 4; tl++) {
                size_t so = (size_t)(4 + tl) * 8192 + (size_t)tid * 16;
                size_t lo = (size_t)tl * 8192 + (size_t)tid * 16;
                gload16(a0 + so, lds0 + lo);
                gload16(a0 + so + 4096, lds0 + lo + 4096);
                gload16(a1 + so, lds0 + 32768 + lo);
                gload16(a1 + so + 4096, lds0 + 32768 + lo + 4096);
            }
            __syncthreads();   // DMA drain #2
        }
    }

    // bias + relu + split-bf16, packed H | L<<16 per element
    unsigned hidp[2][4][4][4];
    #pragma unroll
    for (int nh = 0; nh < 2; nh++)
        #pragma unroll
        for (int mt = 0; mt < 4; mt++)
            #pragma unroll
            for (int nt = 0; nt < 4; nt++)
                #pragma unroll
                for (int rr = 0; rr < 4; rr++) {
                    int col = nh * 128 + wn + nt * 16 + (lane & 15);
                    float v = acc1[nh][mt][nt][rr] + bagg[col];
                    v = fmaxf(v, 0.f);
                    __bf16 hh = (__bf16)v;
                    __bf16 hl = (__bf16)(v - (float)hh);
                    hidp[nh][mt][nt][rr] =
                        (unsigned)bfbits(hh) | ((unsigned)bfbits(hl) << 16);
                }

    // ---- phase B: out = x + relu(hid @ Wff + bff).
    // hid exchanged one k-half at a time: H ushorts [0,16384), L [16384,32768)
    unsigned short* w16 = (unsigned short*)lds0;
    const __bf16*   lB  = (const __bf16*)lds0;

    #pragma unroll
    for (int oh = 0; oh < 2; oh++) {
        const __bf16* f0 = WfHP + (size_t)oh * 32768;
        const __bf16* f1 = WfLP + (size_t)oh * 32768;
        f32x4 acc2[4][4];
        #pragma unroll
        for (int i = 0; i < 4; i++)
            #pragma unroll
            for (int j = 0; j < 4; j++) acc2[i][j] = (f32x4)(0.f);

        #pragma unroll
        for (int kh = 0; kh < 2; kh++) {
            __syncthreads();   // prior LDS reads done
            // write hid k-half kh (= acc half nh=kh), slots sl=0..3
            #pragma unroll
            for (int sl = 0; sl < 4; sl++) {
                if (wn == ((sl >= 2) ? 64 : 0)) {
                    int nt0 = (sl & 1) * 2;
                    #pragma unroll
                    for (int mt = 0; mt < 4; mt++)
                        #pragma unroll
                        for (int j = 0; j < 2; j++) {
                            int nt = nt0 + j;
                            int kc = (wn + nt * 16 + (lane & 15)) - 32 * sl;  // 0..31
                            int ks = kc >> 3, e = kc & 7;
                            #pragma unroll
                            for (int rr = 0; rr < 4; rr++) {
                                int row = wm + mt * 16 + (lane >> 4) * 4 + rr;
                                unsigned u = hidp[kh][mt][nt][rr];
                                w16[(size_t)sl * 4096 + ks * 1024 + row * 8 + e] =
                                    (unsigned short)(u & 0xffffu);
                                w16[16384 + (size_t)sl * 4096 + ks * 1024 + row * 8 + e] =
                                    (unsigned short)(u >> 16);
                            }
                        }
                }
            }
            __syncthreads();   // ds-writes visible
            // compute steps t = kh*4 .. kh*4+3, barrier-free (LDS read-only)
            #pragma unroll
            for (int tl = 0; tl < 4; tl++) {
                int t = kh * 4 + tl;
                bf16x8 a2h[4], a2l[4], b2h[4], b2l[4];
                #pragma unroll
                for (int mt = 0; mt < 4; mt++) {
                    size_t ai = (size_t)tl * 4096 + (size_t)h * 1024 + (size_t)(m_base + mt * 16) * 8;
                    a2h[mt] = *(const bf16x8*)&lB[ai];
                    a2l[mt] = *(const bf16x8*)&lB[16384 + ai];
                }
                #pragma unroll
                for (int nt = 0; nt < 4; nt++) {
                    size_t bi = (size_t)t * 4096 + (size_t)h * 1024 + (size_t)(n_base + nt * 16) * 8;
                    b2h[nt] = *(const bf16x8*)(f0 + bi);
                    b2l[nt] = *(const bf16x8*)(f1 + bi);
                }
                #pragma unroll
                for (int mt = 0; mt < 4; mt++)
                    #pragma unroll
                    for (int nt = 0; nt < 4; nt++) {
                        acc2[mt][nt] = __builtin_amdgcn_mfma_f32_16x16x32_bf16(a2h[mt], b2h[nt], acc2[mt][nt], 0, 0, 0);
                        acc2[mt][nt] = __builtin_amdgcn_mfma_f32_16x16x32_bf16(a2l[mt], b2h[nt], acc2[mt][nt], 0, 0, 0);
                        acc2[mt][nt] = __builtin_amdgcn_mfma_f32_16x16x32_bf16(a2h[mt], b2l[nt], acc2[mt][nt], 0, 0, 0);
                    }
            }
        }
        // epilogue for this out col-half
        #pragma unroll
        for (int mt = 0; mt < 4; mt++)
            #pragma unroll
            for (int nt = 0; nt < 4; nt++) {
                int oc = oh * 128 + wn + nt * 16 + (lane & 15);
                #pragma unroll
                for (int rr = 0; rr < 4; rr++) {
                    int row = row0 + wm + mt * 16 + (lane >> 4) * 4 + rr;
                    if (row < N_NODES) {
                        float v = acc2[mt][nt][rr] + bff[oc];
                        v = fmaxf(v, 0.f);
                        size_t idx = (size_t)row * 256 + oc;
                        out[idx] = v + x[idx];
                    }
                }
            }
    }
}

extern "C" void kernel_launch(void* const* d_in, const int* in_sizes, int n_in,
                              void* d_out, int out_size, void* d_ws, size_t ws_size,
                              hipStream_t stream) {
    const float* x    = (const float*)d_in[0];
    const int*   edge = (const int*)d_in[1];
    const int*   recv = edge;
    const int*   send = edge + M_EDGES;
    const float* Wk   = (const float*)d_in[2];
    const float* bk   = (const float*)d_in[3];
    const float* Wq   = (const float*)d_in[4];
    const float* bq   = (const float*)d_in[5];
    const float* Wv   = (const float*)d_in[6];
    const float* bv   = (const float*)d_in[7];
    const float* Wagg = (const float*)d_in[8];
    const float* bagg = (const float*)d_in[9];
    const float* Wff  = (const float*)d_in[10];
    const float* bff  = (const float*)d_in[11];
    float* out = (float*)d_out;

    float*  Qbuf  = (float*)d_ws;                       // RP*256 f32 (row-major)
    float*  reg2  = Qbuf + (size_t)RP * 256;            // RP*256 f32 multi-use
    float*  qks   = reg2 + (size_t)RP * 256;
    __bf16* Kbf   = (__bf16*)(qks + (size_t)M_EDGES * 8);
    __bf16* Vbf   = Kbf + (size_t)RP * 256;
    int* counts   = (int*)(Vbf + (size_t)RP * 256);
    int* cursor   = counts + N_NODES;
    int* offsets  = cursor + N_NODES;
    int* ssorted  = offsets + N_NODES + 1;
    unsigned* gmax = (unsigned*)(ssorted + M_EDGES);
    __bf16* wt    = (__bf16*)(gmax + 1);
    __bf16* WHq = wt;                    // fused QKV panel, 6 blocks
    __bf16* WLq = wt + 3 * 65536;
    __bf16* WaH = wt + 6 * 65536;  __bf16* WaL = wt + 7 * 65536;
    __bf16* WfH = wt + 8 * 65536;  __bf16* WfL = wt + 9 * 65536;
    float* bqkv = (float*)(wt + 10 * 65536);   // [768]
    __bf16* xh   = (__bf16*)reg2;
    __bf16* xl   = xh + (size_t)RP * 256;
    int*    rsorted = (int*)reg2;
    __bf16* msgH = (__bf16*)reg2;
    __bf16* msgL = msgH + (size_t)RP * 256;

    dim3 blk(256);
    dim3 edge_grid((M_EDGES + 255) / 256);

    // 1) prep (panel weights, panel x split, bias concat, zeroing)
    hipLaunchKernelGGL(prep_kernel, dim3(2048), blk, 0, stream,
                       Wk, Wq, Wv, Wagg, Wff, bk, bq, bv, x,
                       WHq, WLq, WaH, WaL, WfH, WfL, bqkv, xh, xl,
                       counts, cursor, gmax);
    // 2) fused K|Q|V GEMM (panel-staged + XCD swizzle) [control]
    hipLaunchKernelGGL(gemm_qkv, dim3(2346), blk, 0, stream,
                       xh, xl, WHq, WLq, bqkv, Kbf, Qbuf, Vbf);
    // 3) CSR build
    hipLaunchKernelGGL(hist_kernel, edge_grid, blk, 0, stream, recv, counts);
    hipLaunchKernelGGL(scan_kernel, dim3(1), blk, 0, stream, counts, offsets);
    hipLaunchKernelGGL(fill_kernel, edge_grid, blk, 0, stream, recv, send, offsets,
                       cursor, ssorted, rsorted);
    // 4) edge logits + global max
    hipLaunchKernelGGL(qk_csr_kernel, dim3(1024), blk, 0, stream,
                       ssorted, rsorted, Qbuf, (const unsigned short*)Kbf, qks, gmax);
    // 5) segment softmax + aggregate -> panel split-bf16 msg
    hipLaunchKernelGGL(node_agg_kernel, dim3(2048), blk, 0, stream,
                       offsets, ssorted, qks, (const unsigned short*)Vbf, gmax,
                       msgH, msgL);
    // 6) fused output MLP (barrier-minimal, B-from-L2; hid stays on-chip)
    hipLaunchKernelGGL(mlp_fused, dim3((N_NODES + 127) / 128), blk, 0, stream,
                       msgH, msgL, WaH, WaL, WfH, WfL, bagg, bff, x, out);
}

// Round 11
// 769.452 us; speedup vs baseline: 1.0921x; 1.0729x over previous
//
#include <hip/hip_runtime.h>

#define N_NODES 50000
#define M_EDGES 800000
#define RP 50048  // padded row count for matrix buffers (391 blocks of 128)

typedef __bf16 bf16x8 __attribute__((ext_vector_type(8)));
typedef __bf16 bf16x4 __attribute__((ext_vector_type(4)));
typedef float  f32x4  __attribute__((ext_vector_type(4)));

static __device__ __forceinline__ unsigned enc_ord(float f) {
    unsigned b = __float_as_uint(f);
    return (b & 0x80000000u) ? ~b : (b | 0x80000000u);
}
static __device__ __forceinline__ float dec_ord(unsigned u) {
    unsigned b = (u & 0x80000000u) ? (u ^ 0x80000000u) : ~u;
    return __uint_as_float(b);
}
// bf16 pair packed in a uint: lo = bits[15:0], hi = bits[31:16]
static __device__ __forceinline__ float bflo(unsigned u) { return __uint_as_float(u << 16); }
static __device__ __forceinline__ float bfhi(unsigned u) { return __uint_as_float(u & 0xffff0000u); }
static __device__ __forceinline__ unsigned short bfbits(__bf16 b) {
    unsigned short u; __builtin_memcpy(&u, &b, 2); return u;
}

// PANEL layout: operand plane stored per 128-row block as 8 K-step chunks of
// 8KB, each [4 kslots][128 rows][8 elems] bf16 — EXACTLY the LDS staging order.
static __device__ __forceinline__ size_t PE(int m, int k) {
    return (size_t)(m >> 7) * 32768 + (size_t)(k >> 5) * 4096 +
           (size_t)((k >> 3) & 3) * 1024 + (size_t)(m & 127) * 8 + (k & 7);
}

// async 16B global -> LDS DMA (LDS dest = wave-uniform base + lane*16)
static __device__ __forceinline__ void gload16(const void* g, void* l) {
    __builtin_amdgcn_global_load_lds(
        (const __attribute__((address_space(1))) void*)g,
        (__attribute__((address_space(3))) void*)l, 16, 0, 0);
}

// Panel staging: per step t, 8KB per plane, sequential lane-coalesced reads.
static __device__ __forceinline__ void stage_panel(
    const char* a0, const char* a1, const char* b0, const char* b1,
    char* lds0, int buf, int t, int tid) {
    size_t so = (size_t)t * 8192 + (size_t)tid * 16;
    size_t lo = (size_t)buf * 32768 + (size_t)tid * 16;
    gload16(a0 + so, lds0 + lo);
    gload16(a0 + so + 4096, lds0 + lo + 4096);
    gload16(a1 + so, lds0 + 8192 + lo);
    gload16(a1 + so + 4096, lds0 + 8192 + lo + 4096);
    gload16(b0 + so, lds0 + 16384 + lo);
    gload16(b0 + so + 4096, lds0 + 16384 + lo + 4096);
    gload16(b1 + so, lds0 + 24576 + lo);
    gload16(b1 + so + 4096, lds0 + 24576 + lo + 4096);
}

// ---- ONE prep dispatch [verbatim, passing]
__global__ __launch_bounds__(256) void prep_kernel(
    const float* __restrict__ Wk, const float* __restrict__ Wq,
    const float* __restrict__ Wv, const float* __restrict__ Wagg,
    const float* __restrict__ Wff,
    const float* __restrict__ bk, const float* __restrict__ bq,
    const float* __restrict__ bv,
    const float* __restrict__ X,
    __bf16* __restrict__ WHq, __bf16* __restrict__ WLq,
    __bf16* __restrict__ WaH, __bf16* __restrict__ WaL,
    __bf16* __restrict__ WfH, __bf16* __restrict__ WfL,
    float* __restrict__ bqkv, __bf16* __restrict__ xh, __bf16* __restrict__ xl,
    int* __restrict__ counts, int* __restrict__ cursor, unsigned* __restrict__ gmax) {
    int gid = blockIdx.x * 256 + threadIdx.x;
    int stride = gridDim.x * 256;
    for (int i = gid; i < 65536; i += stride) {
        int n = i >> 8, k = i & 255;
        size_t src = (size_t)k * 256 + n;
        float v; __bf16 h;
        v = Wk[src];   h = (__bf16)v; WHq[PE(n, k)] = h;
                       WLq[PE(n, k)] = (__bf16)(v - (float)h);
        v = Wq[src];   h = (__bf16)v; WHq[PE(n + 256, k)] = h;
                       WLq[PE(n + 256, k)] = (__bf16)(v - (float)h);
        v = Wv[src];   h = (__bf16)v; WHq[PE(n + 512, k)] = h;
                       WLq[PE(n + 512, k)] = (__bf16)(v - (float)h);
        v = Wagg[src]; h = (__bf16)v; WaH[PE(n, k)] = h;
                       WaL[PE(n, k)] = (__bf16)(v - (float)h);
        v = Wff[src];  h = (__bf16)v; WfH[PE(n, k)] = h;
                       WfL[PE(n, k)] = (__bf16)(v - (float)h);
    }
    const size_t nx = (size_t)N_NODES * 256 / 4;
    for (size_t i = gid; i < nx; i += stride) {
        float4 v = *(const float4*)(X + i * 4);
        int n = (int)(i >> 6), k0 = (int)((i * 4) & 255);
        bf16x4 hh, ll;
        hh[0] = (__bf16)v.x; ll[0] = (__bf16)(v.x - (float)hh[0]);
        hh[1] = (__bf16)v.y; ll[1] = (__bf16)(v.y - (float)hh[1]);
        hh[2] = (__bf16)v.z; ll[2] = (__bf16)(v.z - (float)hh[2]);
        hh[3] = (__bf16)v.w; ll[3] = (__bf16)(v.w - (float)hh[3]);
        size_t idx = PE(n, k0);
        *(bf16x4*)(xh + idx) = hh;
        *(bf16x4*)(xl + idx) = ll;
    }
    for (int i = gid; i < 768; i += stride)
        bqkv[i] = (i < 256) ? bk[i] : ((i < 512) ? bq[i - 256] : bv[i - 512]);
    for (int i = gid; i < N_NODES; i += stride) { counts[i] = 0; cursor[i] = 0; }
    if (gid == 0) *gmax = 0u;
}

// ---- FUSED K|Q|V projection GEMM [verbatim, passing; control dispatch]
__global__ __launch_bounds__(256) void gemm_qkv(
    const __bf16* __restrict__ AhP, const __bf16* __restrict__ AlP,
    const __bf16* __restrict__ BhP, const __bf16* __restrict__ BlP,
    const float* __restrict__ bqkv,
    __bf16* __restrict__ Kb, float* __restrict__ Qo, __bf16* __restrict__ Vb) {
    __shared__ __attribute__((aligned(16))) __bf16 sm[2][4][4][128][8];

    const int NB = 2346, q = NB / 8, r = NB % 8;   // 293, 2
    int bid = blockIdx.x;
    int xcd = bid & 7, i0 = bid >> 3;
    int logical = (xcd < r ? xcd * (q + 1) : r * (q + 1) + (xcd - r) * q) + i0;
    int by = logical % 6;
    int bx = logical / 6;
    int row0 = bx * 128;
    int n0   = by * 128;

    int tid  = threadIdx.x;
    int lane = tid & 63, wave = tid >> 6;
    int wm = (wave >> 1) * 64, wn = (wave & 1) * 64;

    f32x4 acc[4][4];
    #pragma unroll
    for (int i = 0; i < 4; i++)
        #pragma unroll
        for (int j = 0; j < 4; j++) acc[i][j] = (f32x4)(0.f);

    const char* a0 = (const char*)AhP + (size_t)bx * 65536;
    const char* a1 = (const char*)AlP + (size_t)bx * 65536;
    const char* b0 = (const char*)BhP + (size_t)by * 65536;
    const char* b1 = (const char*)BlP + (size_t)by * 65536;
    char* lds0 = (char*)&sm[0][0][0][0][0];

    stage_panel(a0, a1, b0, b1, lds0, 0, 0, tid);
    __syncthreads();

    int h = lane >> 4;
    int m_base = wm + (lane & 15);
    int n_base = wn + (lane & 15);

    for (int t = 0; t < 8; t++) {
        int cur = t & 1;
        if (t < 7) stage_panel(a0, a1, b0, b1, lds0, cur ^ 1, t + 1, tid);
        bf16x8 ahf[4], alf[4], bhf[4], blf[4];
        #pragma unroll
        for (int mt = 0; mt < 4; mt++) {
            ahf[mt] = *(const bf16x8*)&sm[cur][0][h][m_base + mt * 16][0];
            alf[mt] = *(const bf16x8*)&sm[cur][1][h][m_base + mt * 16][0];
        }
        #pragma unroll
        for (int nt = 0; nt < 4; nt++) {
            bhf[nt] = *(const bf16x8*)&sm[cur][2][h][n_base + nt * 16][0];
            blf[nt] = *(const bf16x8*)&sm[cur][3][h][n_base + nt * 16][0];
        }
        #pragma unroll
        for (int mt = 0; mt < 4; mt++)
            #pragma unroll
            for (int nt = 0; nt < 4; nt++) {
                acc[mt][nt] = __builtin_amdgcn_mfma_f32_16x16x32_bf16(ahf[mt], bhf[nt], acc[mt][nt], 0, 0, 0);
                acc[mt][nt] = __builtin_amdgcn_mfma_f32_16x16x32_bf16(alf[mt], bhf[nt], acc[mt][nt], 0, 0, 0);
                acc[mt][nt] = __builtin_amdgcn_mfma_f32_16x16x32_bf16(ahf[mt], blf[nt], acc[mt][nt], 0, 0, 0);
            }
        __syncthreads();
    }

    #pragma unroll
    for (int mt = 0; mt < 4; mt++) {
        #pragma unroll
        for (int nt = 0; nt < 4; nt++) {
            int cg = n0 + wn + nt * 16 + (lane & 15);
            #pragma unroll
            for (int rr = 0; rr < 4; rr++) {
                int row = row0 + wm + mt * 16 + (lane >> 4) * 4 + rr;
                if (row < N_NODES) {
                    float v = acc[mt][nt][rr] + bqkv[cg];
                    if (cg < 256)      Kb[(size_t)row * 256 + cg] = (__bf16)v;
                    else if (cg < 512) Qo[(size_t)row * 256 + (cg - 256)] = v;
                    else               Vb[(size_t)row * 256 + (cg - 512)] = (__bf16)v;
                }
            }
        }
    }
}

// ---- CSR build [verbatim, passing] ----
__global__ void hist_kernel(const int* __restrict__ recv, int* __restrict__ counts) {
    int t = blockIdx.x * 256 + threadIdx.x;
    if (t < M_EDGES) atomicAdd(&counts[recv[t]], 1);
}

__global__ void scan_kernel(const int* __restrict__ counts, int* __restrict__ offsets) {
    __shared__ int part[256];
    int t = threadIdx.x;
    const int per = (N_NODES + 255) / 256;
    int start = t * per;
    int end = min(start + per, N_NODES);
    int s = 0;
    for (int i = start; i < end; i++) s += counts[i];
    part[t] = s;
    __syncthreads();
    if (t == 0) {
        int acc = 0;
        for (int i = 0; i < 256; i++) { int v = part[i]; part[i] = acc; acc += v; }
    }
    __syncthreads();
    int acc = part[t];
    for (int i = start; i < end; i++) { offsets[i] = acc; acc += counts[i]; }
    if (end == N_NODES && start < N_NODES) offsets[N_NODES] = acc;
}

__global__ void fill_kernel(const int* __restrict__ recv, const int* __restrict__ send,
                            const int* __restrict__ offsets,
                            int* __restrict__ cursor, int* __restrict__ ssorted,
                            int* __restrict__ rsorted) {
    int t = blockIdx.x * 256 + threadIdx.x;
    if (t < M_EDGES) {
        int r = recv[t];
        int pos = offsets[r] + atomicAdd(&cursor[r], 1);
        ssorted[pos] = send[t];
        rsorted[pos] = r;
    }
}

// ---- edge logits [verbatim, passing: ~121 us @ 1024 blocks]
__global__ __launch_bounds__(256) void qk_csr_kernel(
    const int* __restrict__ ssorted, const int* __restrict__ rsorted,
    const float* __restrict__ Q, const unsigned short* __restrict__ Kb,
    float* __restrict__ qks, unsigned* __restrict__ gmax) {
    int wave_id = (blockIdx.x * 256 + threadIdx.x) >> 6;
    int lane = threadIdx.x & 63;
    int e_slot = lane >> 5;
    int sl = lane & 31;
    const int nwaves = (gridDim.x * 256) >> 6;
    const int npairs = M_EDGES / 2;
    float wmax = -INFINITY;
    for (int pp = wave_id; pp < npairs; pp += 4 * nwaves) {
        int ep[4]; bool valid[4];
        #pragma unroll
        for (int u = 0; u < 4; u++) {
            int p = pp + u * nwaves;
            valid[u] = p < npairs;
            ep[u] = (valid[u] ? p : pp) * 2 + e_slot;
        }
        int si[4], ri[4];
        #pragma unroll
        for (int u = 0; u < 4; u++) { si[u] = ssorted[ep[u]]; ri[u] = rsorted[ep[u]]; }
        uint4 kv[4]; float4 qa[4], qb[4];
        #pragma unroll
        for (int u = 0; u < 4; u++) {
            kv[u] = *(const uint4*)(Kb + (size_t)si[u] * 256 + sl * 8);
            qa[u] = *(const float4*)(Q + (size_t)ri[u] * 256 + sl * 8);
            qb[u] = *(const float4*)(Q + (size_t)ri[u] * 256 + sl * 8 + 4);
        }
        #pragma unroll
        for (int u = 0; u < 4; u++) {
            float d = qa[u].x * bflo(kv[u].x) + qa[u].y * bfhi(kv[u].x)
                    + qa[u].z * bflo(kv[u].y) + qa[u].w * bfhi(kv[u].y)
                    + qb[u].x * bflo(kv[u].z) + qb[u].y * bfhi(kv[u].z)
                    + qb[u].z * bflo(kv[u].w) + qb[u].w * bfhi(kv[u].w);
            d += __shfl_xor(d, 1);
            d += __shfl_xor(d, 2);
            wmax = fmaxf(wmax, d);
            if ((sl & 3) == 0 && valid[u])
                qks[(size_t)ep[u] * 8 + (sl >> 2)] = d;
        }
    }
    wmax = fmaxf(wmax, __shfl_xor(wmax, 1));
    wmax = fmaxf(wmax, __shfl_xor(wmax, 2));
    wmax = fmaxf(wmax, __shfl_xor(wmax, 4));
    wmax = fmaxf(wmax, __shfl_xor(wmax, 8));
    wmax = fmaxf(wmax, __shfl_xor(wmax, 16));
    wmax = fmaxf(wmax, __shfl_xor(wmax, 32));
    if (lane == 0 && wmax > -INFINITY) atomicMax(gmax, enc_ord(wmax));
}

// ---- node aggregation [verbatim, passing]
__global__ __launch_bounds__(256) void node_agg_kernel(
    const int* __restrict__ offsets, const int* __restrict__ ssorted,
    const float* __restrict__ qks, const unsigned short* __restrict__ Vb,
    const unsigned* __restrict__ gmax,
    __bf16* __restrict__ msgH, __bf16* __restrict__ msgL) {
    int wave_id = (blockIdx.x * 256 + threadIdx.x) >> 6;
    int lane = threadIdx.x & 63;
    int h = lane >> 3;
    const int nwaves = (gridDim.x * 256) >> 6;
    const int per = (N_NODES + nwaves - 1) / nwaves;
    int n0 = wave_id * per;
    int nend = min(n0 + per, N_NODES);
    float scale = 3.0f / dec_ord(*gmax);
    for (int n = n0; n < nend; n++) {
        int off = offsets[n];
        int deg = offsets[n + 1] - off;
        float sum = 0.f, a0 = 0.f, a1 = 0.f, a2 = 0.f, a3 = 0.f;
        for (int b = 0; b < deg; b += 64) {
            int bn = min(64, deg - b);
            int idxb = ssorted[off + b + min(lane, bn - 1)];
            #define VROW(i) (*(const uint2*)(Vb + \
                (size_t)__shfl(idxb, min((i), bn - 1)) * 256 + lane * 4))
            #define QKL(i) qks[(size_t)(off + b + min((i), bn - 1)) * 8 + h]
            uint2 v0 = VROW(0);
            uint2 v1 = VROW(1);
            float q0 = QKL(0);
            float q1 = QKL(1);
            for (int i = 0; i < bn; i++) {
                uint2 vc = v0; v0 = v1; v1 = VROW(i + 2);
                float qc = q0; q0 = q1; q1 = QKL(i + 2);
                float a = __expf(qc * scale);
                sum += a;
                a0 += a * bflo(vc.x); a1 += a * bfhi(vc.x);
                a2 += a * bflo(vc.y); a3 += a * bfhi(vc.y);
            }
            #undef VROW
            #undef QKL
        }
        float inv = (deg > 0) ? 1.0f / (sum * 5.65685424949238f) : 0.f;  // sqrt(32)
        float r0 = fmaxf(a0 * inv, 0.f), r1 = fmaxf(a1 * inv, 0.f);
        float r2 = fmaxf(a2 * inv, 0.f), r3 = fmaxf(a3 * inv, 0.f);
        bf16x4 hv, lv;
        hv[0] = (__bf16)r0; lv[0] = (__bf16)(r0 - (float)hv[0]);
        hv[1] = (__bf16)r1; lv[1] = (__bf16)(r1 - (float)hv[1]);
        hv[2] = (__bf16)r2; lv[2] = (__bf16)(r2 - (float)hv[2]);
        hv[3] = (__bf16)r3; lv[3] = (__bf16)(r3 - (float)hv[3]);
        size_t idx = PE(n, lane * 4);
        *(bf16x4*)(msgH + idx) = hv;
        *(bf16x4*)(msgL + idx) = lv;
    }
}

// ---- FUSED MLP, 64-ROW TILES (782 blocks): out = x + relu(relu(msg@Wa+ba)@Wf+bf).
// Per block: 64 rows; 4 waves each own a 64-col strip (all 256 cols in one pass).
// A (msg) staged half-K into 32KB LDS (2 DMA drains); B (Wagg/Wff, L2-hot) read
// directly from global panels. Phase B: hid exchanged per k-half via LDS
// (ds_write barriers only). Per-output-element accumulation order unchanged
// (k ascending 0..255, hh/lh/hl per 32-step) -> bit-identical.
__global__ __launch_bounds__(256) void mlp_fused(
    const __bf16* __restrict__ msgHP, const __bf16* __restrict__ msgLP,
    const __bf16* __restrict__ WaHP, const __bf16* __restrict__ WaLP,
    const __bf16* __restrict__ WfHP, const __bf16* __restrict__ WfLP,
    const float* __restrict__ bagg, const float* __restrict__ bff,
    const float* __restrict__ x, float* __restrict__ out) {
    __shared__ __attribute__((aligned(16))) __bf16 sm[16384];   // 32 KB

    int row0 = blockIdx.x * 64;
    int p    = blockIdx.x >> 1;   // 128-row panel index
    int sb   = blockIdx.x & 1;    // 64-row half within panel
    int tid  = threadIdx.x;
    int lane = tid & 63, wave = tid >> 6;
    int wn   = wave * 64;         // wave's col strip [wn, wn+64)
    int h    = lane >> 4;         // k-slot
    int ml   = lane & 15;         // fragment row/col base
    char* lds0 = (char*)sm;
    const __bf16* lA = (const __bf16*)sm;

    const char* a0 = (const char*)msgHP + (size_t)p * 65536;
    const char* a1 = (const char*)msgLP + (size_t)p * 65536;

    // stage A half hf: per tl, 4KB/plane; thread tid -> 16B contiguous.
    // src byte = (hf*4+tl)*8192 + (tid>>6)*2048 + sb*1024 + (tid&63)*16
    // dst: H byte tl*4096 + tid*16 ; L byte 16384 + same
#define STAGE_A(hf) do {                                                      \
        _Pragma("unroll")                                                     \
        for (int tl = 0; tl < 4; tl++) {                                      \
            size_t so = (size_t)((hf) * 4 + tl) * 8192 +                      \
                        (size_t)(tid >> 6) * 2048 + (size_t)sb * 1024 +       \
                        (size_t)(tid & 63) * 16;                              \
            size_t lo = (size_t)tl * 4096 + (size_t)tid * 16;                 \
            gload16(a0 + so, lds0 + lo);                                      \
            gload16(a1 + so, lds0 + 16384 + lo);                              \
        }                                                                     \
    } while (0)

    // ---- phase A: hid = relu(msg @ Wagg + bagg); acc[4 mt][4 nt]
    f32x4 acc1[4][4];
    #pragma unroll
    for (int i = 0; i < 4; i++)
        #pragma unroll
        for (int j = 0; j < 4; j++) acc1[i][j] = (f32x4)(0.f);

    STAGE_A(0);
    __syncthreads();   // DMA drain #1

    #pragma unroll
    for (int hf = 0; hf < 2; hf++) {
        #pragma unroll
        for (int tl = 0; tl < 4; tl++) {
            int t = hf * 4 + tl;
            bf16x8 ahf[4], alf[4], bhf[4], blf[4];
            #pragma unroll
            for (int mt = 0; mt < 4; mt++) {
                size_t ai = (size_t)tl * 2048 + (size_t)h * 512 + (size_t)(ml + mt * 16) * 8;
                ahf[mt] = *(const bf16x8*)&lA[ai];
                alf[mt] = *(const bf16x8*)&lA[8192 + ai];
            }
            #pragma unroll
            for (int nt = 0; nt < 4; nt++) {
                int c = wn + nt * 16 + ml;                 // hid col 0..255
                size_t bi = (size_t)(c >> 7) * 32768 + (size_t)t * 4096 +
                            (size_t)h * 1024 + (size_t)(c & 127) * 8;
                bhf[nt] = *(const bf16x8*)(WaHP + bi);
                blf[nt] = *(const bf16x8*)(WaLP + bi);
            }
            #pragma unroll
            for (int mt = 0; mt < 4; mt++)
                #pragma unroll
                for (int nt = 0; nt < 4; nt++) {
                    acc1[mt][nt] = __builtin_amdgcn_mfma_f32_16x16x32_bf16(ahf[mt], bhf[nt], acc1[mt][nt], 0, 0, 0);
                    acc1[mt][nt] = __builtin_amdgcn_mfma_f32_16x16x32_bf16(alf[mt], bhf[nt], acc1[mt][nt], 0, 0, 0);
                    acc1[mt][nt] = __builtin_amdgcn_mfma_f32_16x16x32_bf16(ahf[mt], blf[nt], acc1[mt][nt], 0, 0, 0);
                }
        }
        if (hf == 0) {
            __syncthreads();   // half-0 reads done
            STAGE_A(1);
            __syncthreads();   // DMA drain #2
        }
    }
#undef STAGE_A

    // bias + relu + split-bf16, packed H | L<<16
    unsigned hidp[4][4][4];
    #pragma unroll
    for (int mt = 0; mt < 4; mt++)
        #pragma unroll
        for (int nt = 0; nt < 4; nt++)
            #pragma unroll
            for (int rr = 0; rr < 4; rr++) {
                int col = wn + nt * 16 + ml;
                float v = acc1[mt][nt][rr] + bagg[col];
                v = fmaxf(v, 0.f);
                __bf16 hh = (__bf16)v;
                __bf16 hl = (__bf16)(v - (float)hh);
                hidp[mt][nt][rr] = (unsigned)bfbits(hh) | ((unsigned)bfbits(hl) << 16);
            }

    // ---- phase B: out = x + relu(hid @ Wff + bff); hid exchanged per k-half.
    // LDS elems: H [0,8192), L [8192,16384): [4 tl][4 ks][64 rows][8]
    unsigned short* w16 = (unsigned short*)sm;
    f32x4 acc2[4][4];
    #pragma unroll
    for (int i = 0; i < 4; i++)
        #pragma unroll
        for (int j = 0; j < 4; j++) acc2[i][j] = (f32x4)(0.f);

    #pragma unroll
    for (int kh = 0; kh < 2; kh++) {
        __syncthreads();   // prior LDS reads done
        if ((wave >> 1) == kh) {   // waves owning cols [kh*128, kh*128+128)
            int base = (wave & 1) * 64;
            #pragma unroll
            for (int nt = 0; nt < 4; nt++) {
                int lk = base + nt * 16 + ml;           // local k 0..127
                int tl = lk >> 5, ks = (lk >> 3) & 3, e = lk & 7;
                #pragma unroll
                for (int mt = 0; mt < 4; mt++)
                    #pragma unroll
                    for (int rr = 0; rr < 4; rr++) {
                        int row = mt * 16 + (lane >> 4) * 4 + rr;   // 0..63
                        size_t di = (size_t)tl * 2048 + (size_t)ks * 512 +
                                    (size_t)row * 8 + e;
                        unsigned u = hidp[mt][nt][rr];
                        w16[di] = (unsigned short)(u & 0xffffu);
                        w16[8192 + di] = (unsigned short)(u >> 16);
                    }
            }
        }
        __syncthreads();   // ds-writes visible
        #pragma unroll
        for (int tl = 0; tl < 4; tl++) {
            int t = kh * 4 + tl;
            bf16x8 a2h[4], a2l[4], b2h[4], b2l[4];
            #pragma unroll
            for (int mt = 0; mt < 4; mt++) {
                size_t ai = (size_t)tl * 2048 + (size_t)h * 512 + (size_t)(ml + mt * 16) * 8;
                a2h[mt] = *(const bf16x8*)&lA[ai];
                a2l[mt] = *(const bf16x8*)&lA[8192 + ai];
            }
            #pragma unroll
            for (int nt = 0; nt < 4; nt++) {
                int oc = wn + nt * 16 + ml;              // out col 0..255
                size_t bi = (size_t)(oc >> 7) * 32768 + (size_t)t * 4096 +
                            (size_t)h * 1024 + (size_t)(oc & 127) * 8;
                b2h[nt] = *(const bf16x8*)(WfHP + bi);
                b2l[nt] = *(const bf16x8*)(WfLP + bi);
            }
            #pragma unroll
            for (int mt = 0; mt < 4; mt++)
                #pragma unroll
                for (int nt = 0; nt < 4; nt++) {
                    acc2[mt][nt] = __builtin_amdgcn_mfma_f32_16x16x32_bf16(a2h[mt], b2h[nt], acc2[mt][nt], 0, 0, 0);
                    acc2[mt][nt] = __builtin_amdgcn_mfma_f32_16x16x32_bf16(a2l[mt], b2h[nt], acc2[mt][nt], 0, 0, 0);
                    acc2[mt][nt] = __builtin_amdgcn_mfma_f32_16x16x32_bf16(a2h[mt], b2l[nt], acc2[mt][nt], 0, 0, 0);
                }
        }
    }
    // epilogue
    #pragma unroll
    for (int mt = 0; mt < 4; mt++)
        #pragma unroll
        for (int nt = 0; nt < 4; nt++) {
            int oc = wn + nt * 16 + ml;
            #pragma unroll
            for (int rr = 0; rr < 4; rr++) {
                int row = row0 + mt * 16 + (lane >> 4) * 4 + rr;
                if (row < N_NODES) {
                    float v = acc2[mt][nt][rr] + bff[oc];
                    v = fmaxf(v, 0.f);
                    size_t idx = (size_t)row * 256 + oc;
                    out[idx] = v + x[idx];
                }
            }
        }
}

extern "C" void kernel_launch(void* const* d_in, const int* in_sizes, int n_in,
                              void* d_out, int out_size, void* d_ws, size_t ws_size,
                              hipStream_t stream) {
    const float* x    = (const float*)d_in[0];
    const int*   edge = (const int*)d_in[1];
    const int*   recv = edge;
    const int*   send = edge + M_EDGES;
    const float* Wk   = (const float*)d_in[2];
    const float* bk   = (const float*)d_in[3];
    const float* Wq   = (const float*)d_in[4];
    const float* bq   = (const float*)d_in[5];
    const float* Wv   = (const float*)d_in[6];
    const float* bv   = (const float*)d_in[7];
    const float* Wagg = (const float*)d_in[8];
    const float* bagg = (const float*)d_in[9];
    const float* Wff  = (const float*)d_in[10];
    const float* bff  = (const float*)d_in[11];
    float* out = (float*)d_out;

    float*  Qbuf  = (float*)d_ws;                       // RP*256 f32 (row-major)
    float*  reg2  = Qbuf + (size_t)RP * 256;            // RP*256 f32 multi-use
    float*  qks   = reg2 + (size_t)RP * 256;
    __bf16* Kbf   = (__bf16*)(qks + (size_t)M_EDGES * 8);
    __bf16* Vbf   = Kbf + (size_t)RP * 256;
    int* counts   = (int*)(Vbf + (size_t)RP * 256);
    int* cursor   = counts + N_NODES;
    int* offsets  = cursor + N_NODES;
    int* ssorted  = offsets + N_NODES + 1;
    unsigned* gmax = (unsigned*)(ssorted + M_EDGES);
    __bf16* wt    = (__bf16*)(gmax + 1);
    __bf16* WHq = wt;                    // fused QKV panel, 6 blocks
    __bf16* WLq = wt + 3 * 65536;
    __bf16* WaH = wt + 6 * 65536;  __bf16* WaL = wt + 7 * 65536;
    __bf16* WfH = wt + 8 * 65536;  __bf16* WfL = wt + 9 * 65536;
    float* bqkv = (float*)(wt + 10 * 65536);   // [768]
    __bf16* xh   = (__bf16*)reg2;
    __bf16* xl   = xh + (size_t)RP * 256;
    int*    rsorted = (int*)reg2;
    __bf16* msgH = (__bf16*)reg2;
    __bf16* msgL = msgH + (size_t)RP * 256;

    dim3 blk(256);
    dim3 edge_grid((M_EDGES + 255) / 256);

    // 1) prep (panel weights, panel x split, bias concat, zeroing)
    hipLaunchKernelGGL(prep_kernel, dim3(2048), blk, 0, stream,
                       Wk, Wq, Wv, Wagg, Wff, bk, bq, bv, x,
                       WHq, WLq, WaH, WaL, WfH, WfL, bqkv, xh, xl,
                       counts, cursor, gmax);
    // 2) fused K|Q|V GEMM (panel-staged + XCD swizzle) [control]
    hipLaunchKernelGGL(gemm_qkv, dim3(2346), blk, 0, stream,
                       xh, xl, WHq, WLq, bqkv, Kbf, Qbuf, Vbf);
    // 3) CSR build
    hipLaunchKernelGGL(hist_kernel, edge_grid, blk, 0, stream, recv, counts);
    hipLaunchKernelGGL(scan_kernel, dim3(1), blk, 0, stream, counts, offsets);
    hipLaunchKernelGGL(fill_kernel, edge_grid, blk, 0, stream, recv, send, offsets,
                       cursor, ssorted, rsorted);
    // 4) edge logits + global max
    hipLaunchKernelGGL(qk_csr_kernel, dim3(1024), blk, 0, stream,
                       ssorted, rsorted, Qbuf, (const unsigned short*)Kbf, qks, gmax);
    // 5) segment softmax + aggregate -> panel split-bf16 msg
    hipLaunchKernelGGL(node_agg_kernel, dim3(2048), blk, 0, stream,
                       offsets, ssorted, qks, (const unsigned short*)Vbf, gmax,
                       msgH, msgL);
    // 6) fused output MLP (64-row tiles, 782 blocks; hid stays on-chip)
    hipLaunchKernelGGL(mlp_fused, dim3((N_NODES + 63) / 64), blk, 0, stream,
                       msgH, msgL, WaH, WaL, WfH, WfL, bagg, bff, x, out);
}

// Round 12
// 760.081 us; speedup vs baseline: 1.1056x; 1.0123x over previous
//
#include <hip/hip_runtime.h>

#define N_NODES 50000
#define M_EDGES 800000
#define RP 50048  // padded row count for matrix buffers (391 blocks of 128)

typedef __bf16 bf16x8 __attribute__((ext_vector_type(8)));
typedef __bf16 bf16x4 __attribute__((ext_vector_type(4)));
typedef float  f32x4  __attribute__((ext_vector_type(4)));

static __device__ __forceinline__ unsigned enc_ord(float f) {
    unsigned b = __float_as_uint(f);
    return (b & 0x80000000u) ? ~b : (b | 0x80000000u);
}
static __device__ __forceinline__ float dec_ord(unsigned u) {
    unsigned b = (u & 0x80000000u) ? (u ^ 0x80000000u) : ~u;
    return __uint_as_float(b);
}
// bf16 pair packed in a uint: lo = bits[15:0], hi = bits[31:16]
static __device__ __forceinline__ float bflo(unsigned u) { return __uint_as_float(u << 16); }
static __device__ __forceinline__ float bfhi(unsigned u) { return __uint_as_float(u & 0xffff0000u); }
static __device__ __forceinline__ unsigned short bfbits(__bf16 b) {
    unsigned short u; __builtin_memcpy(&u, &b, 2); return u;
}

// PANEL layout: operand plane stored per 128-row block as 8 K-step chunks of
// 8KB, each [4 kslots][128 rows][8 elems] bf16 — EXACTLY the LDS staging order.
static __device__ __forceinline__ size_t PE(int m, int k) {
    return (size_t)(m >> 7) * 32768 + (size_t)(k >> 5) * 4096 +
           (size_t)((k >> 3) & 3) * 1024 + (size_t)(m & 127) * 8 + (k & 7);
}

// async 16B global -> LDS DMA (LDS dest = wave-uniform base + lane*16)
static __device__ __forceinline__ void gload16(const void* g, void* l) {
    __builtin_amdgcn_global_load_lds(
        (const __attribute__((address_space(1))) void*)g,
        (__attribute__((address_space(3))) void*)l, 16, 0, 0);
}

// Panel staging: per step t, 8KB per plane, sequential lane-coalesced reads.
static __device__ __forceinline__ void stage_panel(
    const char* a0, const char* a1, const char* b0, const char* b1,
    char* lds0, int buf, int t, int tid) {
    size_t so = (size_t)t * 8192 + (size_t)tid * 16;
    size_t lo = (size_t)buf * 32768 + (size_t)tid * 16;
    gload16(a0 + so, lds0 + lo);
    gload16(a0 + so + 4096, lds0 + lo + 4096);
    gload16(a1 + so, lds0 + 8192 + lo);
    gload16(a1 + so + 4096, lds0 + 8192 + lo + 4096);
    gload16(b0 + so, lds0 + 16384 + lo);
    gload16(b0 + so + 4096, lds0 + 16384 + lo + 4096);
    gload16(b1 + so, lds0 + 24576 + lo);
    gload16(b1 + so + 4096, lds0 + 24576 + lo + 4096);
}

// ---- ONE prep dispatch [verbatim, passing]
__global__ __launch_bounds__(256) void prep_kernel(
    const float* __restrict__ Wk, const float* __restrict__ Wq,
    const float* __restrict__ Wv, const float* __restrict__ Wagg,
    const float* __restrict__ Wff,
    const float* __restrict__ bk, const float* __restrict__ bq,
    const float* __restrict__ bv,
    const float* __restrict__ X,
    __bf16* __restrict__ WHq, __bf16* __restrict__ WLq,
    __bf16* __restrict__ WaH, __bf16* __restrict__ WaL,
    __bf16* __restrict__ WfH, __bf16* __restrict__ WfL,
    float* __restrict__ bqkv, __bf16* __restrict__ xh, __bf16* __restrict__ xl,
    int* __restrict__ counts, int* __restrict__ cursor, unsigned* __restrict__ gmax) {
    int gid = blockIdx.x * 256 + threadIdx.x;
    int stride = gridDim.x * 256;
    for (int i = gid; i < 65536; i += stride) {
        int n = i >> 8, k = i & 255;
        size_t src = (size_t)k * 256 + n;
        float v; __bf16 h;
        v = Wk[src];   h = (__bf16)v; WHq[PE(n, k)] = h;
                       WLq[PE(n, k)] = (__bf16)(v - (float)h);
        v = Wq[src];   h = (__bf16)v; WHq[PE(n + 256, k)] = h;
                       WLq[PE(n + 256, k)] = (__bf16)(v - (float)h);
        v = Wv[src];   h = (__bf16)v; WHq[PE(n + 512, k)] = h;
                       WLq[PE(n + 512, k)] = (__bf16)(v - (float)h);
        v = Wagg[src]; h = (__bf16)v; WaH[PE(n, k)] = h;
                       WaL[PE(n, k)] = (__bf16)(v - (float)h);
        v = Wff[src];  h = (__bf16)v; WfH[PE(n, k)] = h;
                       WfL[PE(n, k)] = (__bf16)(v - (float)h);
    }
    const size_t nx = (size_t)N_NODES * 256 / 4;
    for (size_t i = gid; i < nx; i += stride) {
        float4 v = *(const float4*)(X + i * 4);
        int n = (int)(i >> 6), k0 = (int)((i * 4) & 255);
        bf16x4 hh, ll;
        hh[0] = (__bf16)v.x; ll[0] = (__bf16)(v.x - (float)hh[0]);
        hh[1] = (__bf16)v.y; ll[1] = (__bf16)(v.y - (float)hh[1]);
        hh[2] = (__bf16)v.z; ll[2] = (__bf16)(v.z - (float)hh[2]);
        hh[3] = (__bf16)v.w; ll[3] = (__bf16)(v.w - (float)hh[3]);
        size_t idx = PE(n, k0);
        *(bf16x4*)(xh + idx) = hh;
        *(bf16x4*)(xl + idx) = ll;
    }
    for (int i = gid; i < 768; i += stride)
        bqkv[i] = (i < 256) ? bk[i] : ((i < 512) ? bq[i - 256] : bv[i - 512]);
    for (int i = gid; i < N_NODES; i += stride) { counts[i] = 0; cursor[i] = 0; }
    if (gid == 0) *gmax = 0u;
}

// ---- FUSED K|Q|V projection GEMM [as round 11; Q now emitted as bf16]
__global__ __launch_bounds__(256) void gemm_qkv(
    const __bf16* __restrict__ AhP, const __bf16* __restrict__ AlP,
    const __bf16* __restrict__ BhP, const __bf16* __restrict__ BlP,
    const float* __restrict__ bqkv,
    __bf16* __restrict__ Kb, __bf16* __restrict__ Qb, __bf16* __restrict__ Vb) {
    __shared__ __attribute__((aligned(16))) __bf16 sm[2][4][4][128][8];

    const int NB = 2346, q = NB / 8, r = NB % 8;   // 293, 2
    int bid = blockIdx.x;
    int xcd = bid & 7, i0 = bid >> 3;
    int logical = (xcd < r ? xcd * (q + 1) : r * (q + 1) + (xcd - r) * q) + i0;
    int by = logical % 6;
    int bx = logical / 6;
    int row0 = bx * 128;
    int n0   = by * 128;

    int tid  = threadIdx.x;
    int lane = tid & 63, wave = tid >> 6;
    int wm = (wave >> 1) * 64, wn = (wave & 1) * 64;

    f32x4 acc[4][4];
    #pragma unroll
    for (int i = 0; i < 4; i++)
        #pragma unroll
        for (int j = 0; j < 4; j++) acc[i][j] = (f32x4)(0.f);

    const char* a0 = (const char*)AhP + (size_t)bx * 65536;
    const char* a1 = (const char*)AlP + (size_t)bx * 65536;
    const char* b0 = (const char*)BhP + (size_t)by * 65536;
    const char* b1 = (const char*)BlP + (size_t)by * 65536;
    char* lds0 = (char*)&sm[0][0][0][0][0];

    stage_panel(a0, a1, b0, b1, lds0, 0, 0, tid);
    __syncthreads();

    int h = lane >> 4;
    int m_base = wm + (lane & 15);
    int n_base = wn + (lane & 15);

    for (int t = 0; t < 8; t++) {
        int cur = t & 1;
        if (t < 7) stage_panel(a0, a1, b0, b1, lds0, cur ^ 1, t + 1, tid);
        bf16x8 ahf[4], alf[4], bhf[4], blf[4];
        #pragma unroll
        for (int mt = 0; mt < 4; mt++) {
            ahf[mt] = *(const bf16x8*)&sm[cur][0][h][m_base + mt * 16][0];
            alf[mt] = *(const bf16x8*)&sm[cur][1][h][m_base + mt * 16][0];
        }
        #pragma unroll
        for (int nt = 0; nt < 4; nt++) {
            bhf[nt] = *(const bf16x8*)&sm[cur][2][h][n_base + nt * 16][0];
            blf[nt] = *(const bf16x8*)&sm[cur][3][h][n_base + nt * 16][0];
        }
        #pragma unroll
        for (int mt = 0; mt < 4; mt++)
            #pragma unroll
            for (int nt = 0; nt < 4; nt++) {
                acc[mt][nt] = __builtin_amdgcn_mfma_f32_16x16x32_bf16(ahf[mt], bhf[nt], acc[mt][nt], 0, 0, 0);
                acc[mt][nt] = __builtin_amdgcn_mfma_f32_16x16x32_bf16(alf[mt], bhf[nt], acc[mt][nt], 0, 0, 0);
                acc[mt][nt] = __builtin_amdgcn_mfma_f32_16x16x32_bf16(ahf[mt], blf[nt], acc[mt][nt], 0, 0, 0);
            }
        __syncthreads();
    }

    #pragma unroll
    for (int mt = 0; mt < 4; mt++) {
        #pragma unroll
        for (int nt = 0; nt < 4; nt++) {
            int cg = n0 + wn + nt * 16 + (lane & 15);
            #pragma unroll
            for (int rr = 0; rr < 4; rr++) {
                int row = row0 + wm + mt * 16 + (lane >> 4) * 4 + rr;
                if (row < N_NODES) {
                    float v = acc[mt][nt][rr] + bqkv[cg];
                    if (cg < 256)      Kb[(size_t)row * 256 + cg] = (__bf16)v;
                    else if (cg < 512) Qb[(size_t)row * 256 + (cg - 256)] = (__bf16)v;
                    else               Vb[(size_t)row * 256 + (cg - 512)] = (__bf16)v;
                }
            }
        }
    }
}

// ---- CSR build [verbatim, passing] ----
__global__ void hist_kernel(const int* __restrict__ recv, int* __restrict__ counts) {
    int t = blockIdx.x * 256 + threadIdx.x;
    if (t < M_EDGES) atomicAdd(&counts[recv[t]], 1);
}

__global__ void scan_kernel(const int* __restrict__ counts, int* __restrict__ offsets) {
    __shared__ int part[256];
    int t = threadIdx.x;
    const int per = (N_NODES + 255) / 256;
    int start = t * per;
    int end = min(start + per, N_NODES);
    int s = 0;
    for (int i = start; i < end; i++) s += counts[i];
    part[t] = s;
    __syncthreads();
    if (t == 0) {
        int acc = 0;
        for (int i = 0; i < 256; i++) { int v = part[i]; part[i] = acc; acc += v; }
    }
    __syncthreads();
    int acc = part[t];
    for (int i = start; i < end; i++) { offsets[i] = acc; acc += counts[i]; }
    if (end == N_NODES && start < N_NODES) offsets[N_NODES] = acc;
}

__global__ void fill_kernel(const int* __restrict__ recv, const int* __restrict__ send,
                            const int* __restrict__ offsets,
                            int* __restrict__ cursor, int* __restrict__ ssorted,
                            int* __restrict__ rsorted) {
    int t = blockIdx.x * 256 + threadIdx.x;
    if (t < M_EDGES) {
        int r = recv[t];
        int pos = offsets[r] + atomicAdd(&cursor[r], 1);
        ssorted[pos] = send[t];
        rsorted[pos] = r;
    }
}

// ---- edge logits: Q NOW bf16 -> 2 uint4 gathers per edge (was 3 loads),
// 12 vmem/4-slot-iter (was 20). Same sliding-window grid-stride, same
// reduction structure (sl covers dims [sl*8, sl*8+8); head = sl>>2).
__global__ __launch_bounds__(256) void qk_csr_kernel(
    const int* __restrict__ ssorted, const int* __restrict__ rsorted,
    const unsigned short* __restrict__ Qb, const unsigned short* __restrict__ Kb,
    float* __restrict__ qks, unsigned* __restrict__ gmax) {
    int wave_id = (blockIdx.x * 256 + threadIdx.x) >> 6;
    int lane = threadIdx.x & 63;
    int e_slot = lane >> 5;
    int sl = lane & 31;
    const int nwaves = (gridDim.x * 256) >> 6;
    const int npairs = M_EDGES / 2;
    float wmax = -INFINITY;
    for (int pp = wave_id; pp < npairs; pp += 4 * nwaves) {
        int ep[4]; bool valid[4];
        #pragma unroll
        for (int u = 0; u < 4; u++) {
            int p = pp + u * nwaves;
            valid[u] = p < npairs;
            ep[u] = (valid[u] ? p : pp) * 2 + e_slot;
        }
        int si[4], ri[4];
        #pragma unroll
        for (int u = 0; u < 4; u++) { si[u] = ssorted[ep[u]]; ri[u] = rsorted[ep[u]]; }
        uint4 kv[4], qv[4];
        #pragma unroll
        for (int u = 0; u < 4; u++) {
            kv[u] = *(const uint4*)(Kb + (size_t)si[u] * 256 + sl * 8);
            qv[u] = *(const uint4*)(Qb + (size_t)ri[u] * 256 + sl * 8);
        }
        #pragma unroll
        for (int u = 0; u < 4; u++) {
            float d = bflo(qv[u].x) * bflo(kv[u].x) + bfhi(qv[u].x) * bfhi(kv[u].x)
                    + bflo(qv[u].y) * bflo(kv[u].y) + bfhi(qv[u].y) * bfhi(kv[u].y)
                    + bflo(qv[u].z) * bflo(kv[u].z) + bfhi(qv[u].z) * bfhi(kv[u].z)
                    + bflo(qv[u].w) * bflo(kv[u].w) + bfhi(qv[u].w) * bfhi(kv[u].w);
            d += __shfl_xor(d, 1);
            d += __shfl_xor(d, 2);
            wmax = fmaxf(wmax, d);
            if ((sl & 3) == 0 && valid[u])
                qks[(size_t)ep[u] * 8 + (sl >> 2)] = d;
        }
    }
    wmax = fmaxf(wmax, __shfl_xor(wmax, 1));
    wmax = fmaxf(wmax, __shfl_xor(wmax, 2));
    wmax = fmaxf(wmax, __shfl_xor(wmax, 4));
    wmax = fmaxf(wmax, __shfl_xor(wmax, 8));
    wmax = fmaxf(wmax, __shfl_xor(wmax, 16));
    wmax = fmaxf(wmax, __shfl_xor(wmax, 32));
    if (lane == 0 && wmax > -INFINITY) atomicMax(gmax, enc_ord(wmax));
}

// ---- node aggregation [verbatim, passing]
__global__ __launch_bounds__(256) void node_agg_kernel(
    const int* __restrict__ offsets, const int* __restrict__ ssorted,
    const float* __restrict__ qks, const unsigned short* __restrict__ Vb,
    const unsigned* __restrict__ gmax,
    __bf16* __restrict__ msgH, __bf16* __restrict__ msgL) {
    int wave_id = (blockIdx.x * 256 + threadIdx.x) >> 6;
    int lane = threadIdx.x & 63;
    int h = lane >> 3;
    const int nwaves = (gridDim.x * 256) >> 6;
    const int per = (N_NODES + nwaves - 1) / nwaves;
    int n0 = wave_id * per;
    int nend = min(n0 + per, N_NODES);
    float scale = 3.0f / dec_ord(*gmax);
    for (int n = n0; n < nend; n++) {
        int off = offsets[n];
        int deg = offsets[n + 1] - off;
        float sum = 0.f, a0 = 0.f, a1 = 0.f, a2 = 0.f, a3 = 0.f;
        for (int b = 0; b < deg; b += 64) {
            int bn = min(64, deg - b);
            int idxb = ssorted[off + b + min(lane, bn - 1)];
            #define VROW(i) (*(const uint2*)(Vb + \
                (size_t)__shfl(idxb, min((i), bn - 1)) * 256 + lane * 4))
            #define QKL(i) qks[(size_t)(off + b + min((i), bn - 1)) * 8 + h]
            uint2 v0 = VROW(0);
            uint2 v1 = VROW(1);
            float q0 = QKL(0);
            float q1 = QKL(1);
            for (int i = 0; i < bn; i++) {
                uint2 vc = v0; v0 = v1; v1 = VROW(i + 2);
                float qc = q0; q0 = q1; q1 = QKL(i + 2);
                float a = __expf(qc * scale);
                sum += a;
                a0 += a * bflo(vc.x); a1 += a * bfhi(vc.x);
                a2 += a * bflo(vc.y); a3 += a * bfhi(vc.y);
            }
            #undef VROW
            #undef QKL
        }
        float inv = (deg > 0) ? 1.0f / (sum * 5.65685424949238f) : 0.f;  // sqrt(32)
        float r0 = fmaxf(a0 * inv, 0.f), r1 = fmaxf(a1 * inv, 0.f);
        float r2 = fmaxf(a2 * inv, 0.f), r3 = fmaxf(a3 * inv, 0.f);
        bf16x4 hv, lv;
        hv[0] = (__bf16)r0; lv[0] = (__bf16)(r0 - (float)hv[0]);
        hv[1] = (__bf16)r1; lv[1] = (__bf16)(r1 - (float)hv[1]);
        hv[2] = (__bf16)r2; lv[2] = (__bf16)(r2 - (float)hv[2]);
        hv[3] = (__bf16)r3; lv[3] = (__bf16)(r3 - (float)hv[3]);
        size_t idx = PE(n, lane * 4);
        *(bf16x4*)(msgH + idx) = hv;
        *(bf16x4*)(msgL + idx) = lv;
    }
}

// ---- FUSED MLP, 64-ROW TILES (782 blocks) [verbatim, passing]
__global__ __launch_bounds__(256) void mlp_fused(
    const __bf16* __restrict__ msgHP, const __bf16* __restrict__ msgLP,
    const __bf16* __restrict__ WaHP, const __bf16* __restrict__ WaLP,
    const __bf16* __restrict__ WfHP, const __bf16* __restrict__ WfLP,
    const float* __restrict__ bagg, const float* __restrict__ bff,
    const float* __restrict__ x, float* __restrict__ out) {
    __shared__ __attribute__((aligned(16))) __bf16 sm[16384];   // 32 KB

    int row0 = blockIdx.x * 64;
    int p    = blockIdx.x >> 1;   // 128-row panel index
    int sb   = blockIdx.x & 1;    // 64-row half within panel
    int tid  = threadIdx.x;
    int lane = tid & 63, wave = tid >> 6;
    int wn   = wave * 64;         // wave's col strip [wn, wn+64)
    int h    = lane >> 4;         // k-slot
    int ml   = lane & 15;         // fragment row/col base
    char* lds0 = (char*)sm;
    const __bf16* lA = (const __bf16*)sm;

    const char* a0 = (const char*)msgHP + (size_t)p * 65536;
    const char* a1 = (const char*)msgLP + (size_t)p * 65536;

#define STAGE_A(hf) do {                                                      \
        _Pragma("unroll")                                                     \
        for (int tl = 0; tl < 4; tl++) {                                      \
            size_t so = (size_t)((hf) * 4 + tl) * 8192 +                      \
                        (size_t)(tid >> 6) * 2048 + (size_t)sb * 1024 +       \
                        (size_t)(tid & 63) * 16;                              \
            size_t lo = (size_t)tl * 4096 + (size_t)tid * 16;                 \
            gload16(a0 + so, lds0 + lo);                                      \
            gload16(a1 + so, lds0 + 16384 + lo);                              \
        }                                                                     \
    } while (0)

    // ---- phase A: hid = relu(msg @ Wagg + bagg); acc[4 mt][4 nt]
    f32x4 acc1[4][4];
    #pragma unroll
    for (int i = 0; i < 4; i++)
        #pragma unroll
        for (int j = 0; j < 4; j++) acc1[i][j] = (f32x4)(0.f);

    STAGE_A(0);
    __syncthreads();   // DMA drain #1

    #pragma unroll
    for (int hf = 0; hf < 2; hf++) {
        #pragma unroll
        for (int tl = 0; tl < 4; tl++) {
            int t = hf * 4 + tl;
            bf16x8 ahf[4], alf[4], bhf[4], blf[4];
            #pragma unroll
            for (int mt = 0; mt < 4; mt++) {
                size_t ai = (size_t)tl * 2048 + (size_t)h * 512 + (size_t)(ml + mt * 16) * 8;
                ahf[mt] = *(const bf16x8*)&lA[ai];
                alf[mt] = *(const bf16x8*)&lA[8192 + ai];
            }
            #pragma unroll
            for (int nt = 0; nt < 4; nt++) {
                int c = wn + nt * 16 + ml;                 // hid col 0..255
                size_t bi = (size_t)(c >> 7) * 32768 + (size_t)t * 4096 +
                            (size_t)h * 1024 + (size_t)(c & 127) * 8;
                bhf[nt] = *(const bf16x8*)(WaHP + bi);
                blf[nt] = *(const bf16x8*)(WaLP + bi);
            }
            #pragma unroll
            for (int mt = 0; mt < 4; mt++)
                #pragma unroll
                for (int nt = 0; nt < 4; nt++) {
                    acc1[mt][nt] = __builtin_amdgcn_mfma_f32_16x16x32_bf16(ahf[mt], bhf[nt], acc1[mt][nt], 0, 0, 0);
                    acc1[mt][nt] = __builtin_amdgcn_mfma_f32_16x16x32_bf16(alf[mt], bhf[nt], acc1[mt][nt], 0, 0, 0);
                    acc1[mt][nt] = __builtin_amdgcn_mfma_f32_16x16x32_bf16(ahf[mt], blf[nt], acc1[mt][nt], 0, 0, 0);
                }
        }
        if (hf == 0) {
            __syncthreads();   // half-0 reads done
            STAGE_A(1);
            __syncthreads();   // DMA drain #2
        }
    }
#undef STAGE_A

    // bias + relu + split-bf16, packed H | L<<16
    unsigned hidp[4][4][4];
    #pragma unroll
    for (int mt = 0; mt < 4; mt++)
        #pragma unroll
        for (int nt = 0; nt < 4; nt++)
            #pragma unroll
            for (int rr = 0; rr < 4; rr++) {
                int col = wn + nt * 16 + ml;
                float v = acc1[mt][nt][rr] + bagg[col];
                v = fmaxf(v, 0.f);
                __bf16 hh = (__bf16)v;
                __bf16 hl = (__bf16)(v - (float)hh);
                hidp[mt][nt][rr] = (unsigned)bfbits(hh) | ((unsigned)bfbits(hl) << 16);
            }

    // ---- phase B: out = x + relu(hid @ Wff + bff); hid exchanged per k-half.
    unsigned short* w16 = (unsigned short*)sm;
    f32x4 acc2[4][4];
    #pragma unroll
    for (int i = 0; i < 4; i++)
        #pragma unroll
        for (int j = 0; j < 4; j++) acc2[i][j] = (f32x4)(0.f);

    #pragma unroll
    for (int kh = 0; kh < 2; kh++) {
        __syncthreads();   // prior LDS reads done
        if ((wave >> 1) == kh) {   // waves owning cols [kh*128, kh*128+128)
            int base = (wave & 1) * 64;
            #pragma unroll
            for (int nt = 0; nt < 4; nt++) {
                int lk = base + nt * 16 + ml;           // local k 0..127
                int tl = lk >> 5, ks = (lk >> 3) & 3, e = lk & 7;
                #pragma unroll
                for (int mt = 0; mt < 4; mt++)
                    #pragma unroll
                    for (int rr = 0; rr < 4; rr++) {
                        int row = mt * 16 + (lane >> 4) * 4 + rr;   // 0..63
                        size_t di = (size_t)tl * 2048 + (size_t)ks * 512 +
                                    (size_t)row * 8 + e;
                        unsigned u = hidp[mt][nt][rr];
                        w16[di] = (unsigned short)(u & 0xffffu);
                        w16[8192 + di] = (unsigned short)(u >> 16);
                    }
            }
        }
        __syncthreads();   // ds-writes visible
        #pragma unroll
        for (int tl = 0; tl < 4; tl++) {
            int t = kh * 4 + tl;
            bf16x8 a2h[4], a2l[4], b2h[4], b2l[4];
            #pragma unroll
            for (int mt = 0; mt < 4; mt++) {
                size_t ai = (size_t)tl * 2048 + (size_t)h * 512 + (size_t)(ml + mt * 16) * 8;
                a2h[mt] = *(const bf16x8*)&lA[ai];
                a2l[mt] = *(const bf16x8*)&lA[8192 + ai];
            }
            #pragma unroll
            for (int nt = 0; nt < 4; nt++) {
                int oc = wn + nt * 16 + ml;              // out col 0..255
                size_t bi = (size_t)(oc >> 7) * 32768 + (size_t)t * 4096 +
                            (size_t)h * 1024 + (size_t)(oc & 127) * 8;
                b2h[nt] = *(const bf16x8*)(WfHP + bi);
                b2l[nt] = *(const bf16x8*)(WfLP + bi);
            }
            #pragma unroll
            for (int mt = 0; mt < 4; mt++)
                #pragma unroll
                for (int nt = 0; nt < 4; nt++) {
                    acc2[mt][nt] = __builtin_amdgcn_mfma_f32_16x16x32_bf16(a2h[mt], b2h[nt], acc2[mt][nt], 0, 0, 0);
                    acc2[mt][nt] = __builtin_amdgcn_mfma_f32_16x16x32_bf16(a2l[mt], b2h[nt], acc2[mt][nt], 0, 0, 0);
                    acc2[mt][nt] = __builtin_amdgcn_mfma_f32_16x16x32_bf16(a2h[mt], b2l[nt], acc2[mt][nt], 0, 0, 0);
                }
        }
    }
    // epilogue
    #pragma unroll
    for (int mt = 0; mt < 4; mt++)
        #pragma unroll
        for (int nt = 0; nt < 4; nt++) {
            int oc = wn + nt * 16 + ml;
            #pragma unroll
            for (int rr = 0; rr < 4; rr++) {
                int row = row0 + mt * 16 + (lane >> 4) * 4 + rr;
                if (row < N_NODES) {
                    float v = acc2[mt][nt][rr] + bff[oc];
                    v = fmaxf(v, 0.f);
                    size_t idx = (size_t)row * 256 + oc;
                    out[idx] = v + x[idx];
                }
            }
        }
}

extern "C" void kernel_launch(void* const* d_in, const int* in_sizes, int n_in,
                              void* d_out, int out_size, void* d_ws, size_t ws_size,
                              hipStream_t stream) {
    const float* x    = (const float*)d_in[0];
    const int*   edge = (const int*)d_in[1];
    const int*   recv = edge;
    const int*   send = edge + M_EDGES;
    const float* Wk   = (const float*)d_in[2];
    const float* bk   = (const float*)d_in[3];
    const float* Wq   = (const float*)d_in[4];
    const float* bq   = (const float*)d_in[5];
    const float* Wv   = (const float*)d_in[6];
    const float* bv   = (const float*)d_in[7];
    const float* Wagg = (const float*)d_in[8];
    const float* bagg = (const float*)d_in[9];
    const float* Wff  = (const float*)d_in[10];
    const float* bff  = (const float*)d_in[11];
    float* out = (float*)d_out;

    float*  Qbuf  = (float*)d_ws;                       // region reused: Q bf16
    float*  reg2  = Qbuf + (size_t)RP * 256;            // RP*256 f32 multi-use
    float*  qks   = reg2 + (size_t)RP * 256;
    __bf16* Kbf   = (__bf16*)(qks + (size_t)M_EDGES * 8);
    __bf16* Vbf   = Kbf + (size_t)RP * 256;
    int* counts   = (int*)(Vbf + (size_t)RP * 256);
    int* cursor   = counts + N_NODES;
    int* offsets  = cursor + N_NODES;
    int* ssorted  = offsets + N_NODES + 1;
    unsigned* gmax = (unsigned*)(ssorted + M_EDGES);
    __bf16* wt    = (__bf16*)(gmax + 1);
    __bf16* WHq = wt;                    // fused QKV panel, 6 blocks
    __bf16* WLq = wt + 3 * 65536;
    __bf16* WaH = wt + 6 * 65536;  __bf16* WaL = wt + 7 * 65536;
    __bf16* WfH = wt + 8 * 65536;  __bf16* WfL = wt + 9 * 65536;
    float* bqkv = (float*)(wt + 10 * 65536);   // [768]
    __bf16* Qbf  = (__bf16*)Qbuf;              // Q stored bf16 row-major
    __bf16* xh   = (__bf16*)reg2;
    __bf16* xl   = xh + (size_t)RP * 256;
    int*    rsorted = (int*)reg2;
    __bf16* msgH = (__bf16*)reg2;
    __bf16* msgL = msgH + (size_t)RP * 256;

    dim3 blk(256);
    dim3 edge_grid((M_EDGES + 255) / 256);

    // 1) prep (panel weights, panel x split, bias concat, zeroing)
    hipLaunchKernelGGL(prep_kernel, dim3(2048), blk, 0, stream,
                       Wk, Wq, Wv, Wagg, Wff, bk, bq, bv, x,
                       WHq, WLq, WaH, WaL, WfH, WfL, bqkv, xh, xl,
                       counts, cursor, gmax);
    // 2) fused K|Q|V GEMM (panel-staged + XCD swizzle; Q emitted bf16)
    hipLaunchKernelGGL(gemm_qkv, dim3(2346), blk, 0, stream,
                       xh, xl, WHq, WLq, bqkv, Kbf, Qbf, Vbf);
    // 3) CSR build
    hipLaunchKernelGGL(hist_kernel, edge_grid, blk, 0, stream, recv, counts);
    hipLaunchKernelGGL(scan_kernel, dim3(1), blk, 0, stream, counts, offsets);
    hipLaunchKernelGGL(fill_kernel, edge_grid, blk, 0, stream, recv, send, offsets,
                       cursor, ssorted, rsorted);
    // 4) edge logits + global max (Q bf16: 2 gathers/edge)
    hipLaunchKernelGGL(qk_csr_kernel, dim3(1024), blk, 0, stream,
                       ssorted, rsorted, (const unsigned short*)Qbf,
                       (const unsigned short*)Kbf, qks, gmax);
    // 5) segment softmax + aggregate -> panel split-bf16 msg
    hipLaunchKernelGGL(node_agg_kernel, dim3(2048), blk, 0, stream,
                       offsets, ssorted, qks, (const unsigned short*)Vbf, gmax,
                       msgH, msgL);
    // 6) fused output MLP (64-row tiles, 782 blocks; hid stays on-chip)
    hipLaunchKernelGGL(mlp_fused, dim3((N_NODES + 63) / 64), blk, 0, stream,
                       msgH, msgL, WaH, WaL, WfH, WfL, bagg, bff, x, out);
}